// Round 2
// baseline (2657.832 us; speedup 1.0000x reference)
//
#include <hip/hip_runtime.h>
#include <math.h>

// Problem dims
#define L_DIM 2048
#define B_DIM 16
#define D_DIM 512
#define H_DIM 1024
#define Z_DIM 128
#define NC    16
#define BASE_N 2176            // Z + H + 2D
#define ROWS  (L_DIM*B_DIM)    // 32768

typedef unsigned short bf16_t;

__device__ __forceinline__ float sigmoidf_(float x){ return 1.f/(1.f+__expf(-x)); }
__device__ __forceinline__ float siluf_(float x){ return x/(1.f+__expf(-x)); }
__device__ __forceinline__ float fbits(unsigned int b){ union{unsigned int i; float f;} c; c.i=b; return c.f; }
__device__ __forceinline__ unsigned short f2bf(float f){
  union{float f; unsigned int i;} c; c.f=f;
  unsigned int r = c.i + 0x7FFFu + ((c.i>>16)&1u);   // round-nearest-even
  return (unsigned short)(r>>16);
}
__device__ __forceinline__ float bf2f(unsigned short u){ return fbits(((unsigned int)u)<<16); }

// 8-element vector loads -> fp32, overloaded on source dtype
__device__ __forceinline__ void load8(const float* __restrict__ p, float* d){
  float4 a = *(const float4*)p; float4 b = *(const float4*)(p+4);
  d[0]=a.x; d[1]=a.y; d[2]=a.z; d[3]=a.w; d[4]=b.x; d[5]=b.y; d[6]=b.z; d[7]=b.w;
}
__device__ __forceinline__ void load8(const bf16_t* __restrict__ p, float* d){
  uint4 u = *(const uint4*)p;
  d[0]=fbits(u.x<<16); d[1]=fbits(u.x&0xFFFF0000u);
  d[2]=fbits(u.y<<16); d[3]=fbits(u.y&0xFFFF0000u);
  d[4]=fbits(u.z<<16); d[5]=fbits(u.z&0xFFFF0000u);
  d[6]=fbits(u.w<<16); d[7]=fbits(u.w&0xFFFF0000u);
}
__device__ __forceinline__ void load4(const bf16_t* __restrict__ p, float* d){
  uint2 u = *(const uint2*)p;
  d[0]=fbits(u.x<<16); d[1]=fbits(u.x&0xFFFF0000u);
  d[2]=fbits(u.y<<16); d[3]=fbits(u.y&0xFFFF0000u);
}
__device__ __forceinline__ void store4(bf16_t* p, float a, float b, float c, float dd){
  uint2 s; s.x = (unsigned int)f2bf(a) | ((unsigned int)f2bf(b)<<16);
  s.y = (unsigned int)f2bf(c) | ((unsigned int)f2bf(dd)<<16);
  *(uint2*)p = s;
}

// ---------------------------------------------------------------------------
// EMA: bidirectional damped EMA == fwd causal IIR + bwd anti-causal IIR.
// fwd writes fp32 partial yf; bwd combines + residual + silu -> bf16 mx.
// One thread per (b,d) chain; wave-coalesced along d.
// ---------------------------------------------------------------------------
__global__ __launch_bounds__(256) void ema_fwd_kernel(
    const float* __restrict__ x, const float* __restrict__ delta,
    const float* __restrict__ alpha, const float* __restrict__ beta,
    const float* __restrict__ gamma, float* __restrict__ yf)
{
  int idx = blockIdx.x*256 + threadIdx.x;   // 0..8191
  int d = idx & (D_DIM-1);
  int b = idx >> 9;
  float p0 = sigmoidf_(delta[d*2+0]);
  float p1 = sigmoidf_(delta[d*2+1]);
  float q0 = 1.f - p0*sigmoidf_(alpha[d*2+0]);
  float q1 = 1.f - p1*sigmoidf_(alpha[d*2+1]);
  const float rs = 0.70710678118654752f;    // 1/sqrt(NDIM)
  float c0 = p0*beta[d*2+0]*gamma[d*2+0]*rs;
  float c1 = p1*beta[d*2+1]*gamma[d*2+1]*rs;
  float h0 = 0.f, h1 = 0.f;
  size_t off = (size_t)b*D_DIM + d;
  for (int t = 0; t < L_DIM; ++t) {
    size_t a = (size_t)t*(B_DIM*D_DIM) + off;
    float xv = x[a];
    h0 = fmaf(q0, h0, xv);
    h1 = fmaf(q1, h1, xv);
    yf[a] = fmaf(c0, h0, c1*h1);
  }
}

__global__ __launch_bounds__(256) void ema_bwd_kernel(
    const float* __restrict__ x, const float* __restrict__ delta,
    const float* __restrict__ alpha, const float* __restrict__ beta,
    const float* __restrict__ gamma, const float* __restrict__ omega,
    const float* __restrict__ yf, bf16_t* __restrict__ mx)
{
  int idx = blockIdx.x*256 + threadIdx.x;
  int d = idx & (D_DIM-1);
  int b = idx >> 9;
  int dd = d + D_DIM;
  float p0 = sigmoidf_(delta[dd*2+0]);
  float p1 = sigmoidf_(delta[dd*2+1]);
  float q0 = 1.f - p0*sigmoidf_(alpha[dd*2+0]);
  float q1 = 1.f - p1*sigmoidf_(alpha[dd*2+1]);
  const float rs = 0.70710678118654752f;
  float c0 = p0*beta[dd*2+0]*gamma[dd*2+0]*rs;
  float c1 = p1*beta[dd*2+1]*gamma[dd*2+1]*rs;
  float om = omega[d];
  float g0 = 0.f, g1 = 0.f;
  size_t off = (size_t)b*D_DIM + d;
  for (int t = L_DIM-1; t >= 0; --t) {
    size_t a = (size_t)t*(B_DIM*D_DIM) + off;
    float xv = x[a];
    g0 = fmaf(q0, g0, xv);
    g1 = fmaf(q1, g1, xv);
    float s = yf[a] + fmaf(c0, g0, c1*g1) + xv*om;
    mx[a] = f2bf(siluf_(s));
  }
}

// ---------------------------------------------------------------------------
// Tiled GEMM: C(bf16) = act(A@W + bias [+ Add(bf16)]) — BM=BN=128, BK=16,
// 256 threads, 8x8 microtile, fp32 LDS/compute. A,W dtype templated.
// act: 0=none, 1=silu.
// ---------------------------------------------------------------------------
template<typename TA, typename TW>
__global__ __launch_bounds__(256) void gemm_kernel(
    const TA* __restrict__ A, const TW* __restrict__ W,
    const float* __restrict__ bias, const bf16_t* __restrict__ Add, int addStride,
    bf16_t* __restrict__ C, int M, int N, int K, int act)
{
  __shared__ float As[16][136];  // [k][m], padded
  __shared__ float Ws[16][128];  // [k][n]
  int bn = blockIdx.x, bm = blockIdx.y;
  int tid = threadIdx.x;
  int tx = tid & 15, ty = tid >> 4;
  float acc[8][8] = {};
  const TA* Ab = A + (size_t)bm*128*K;
  const TW* Wb = W + bn*128;
  int am = tid >> 1, ak = (tid & 1)*8;
  int wk = tid >> 4, wn = (tid & 15)*8;
  for (int k0 = 0; k0 < K; k0 += 16) {
    float t8[8];
    load8(Ab + (size_t)am*K + k0 + ak, t8);
    #pragma unroll
    for (int q = 0; q < 8; ++q) As[ak+q][am] = t8[q];
    load8(Wb + (size_t)(k0+wk)*N + wn, t8);
    #pragma unroll
    for (int q = 0; q < 8; ++q) Ws[wk][wn+q] = t8[q];
    __syncthreads();
    #pragma unroll
    for (int kk = 0; kk < 16; ++kk) {
      float a[8], w[8];
      *(float4*)&a[0] = *(const float4*)&As[kk][ty*8];
      *(float4*)&a[4] = *(const float4*)&As[kk][ty*8+4];
      *(float4*)&w[0] = *(const float4*)&Ws[kk][tx*8];
      *(float4*)&w[4] = *(const float4*)&Ws[kk][tx*8+4];
      #pragma unroll
      for (int i = 0; i < 8; ++i)
        #pragma unroll
        for (int j = 0; j < 8; ++j)
          acc[i][j] = fmaf(a[i], w[j], acc[i][j]);
    }
    __syncthreads();
  }
  #pragma unroll
  for (int i = 0; i < 8; ++i) {
    int gm = bm*128 + ty*8 + i;
    #pragma unroll
    for (int jj = 0; jj < 8; jj += 4) {
      int gn = bn*128 + tx*8 + jj;
      float r0 = acc[i][jj+0] + bias[gn+0];
      float r1 = acc[i][jj+1] + bias[gn+1];
      float r2 = acc[i][jj+2] + bias[gn+2];
      float r3 = acc[i][jj+3] + bias[gn+3];
      if (Add) {
        float a4[4]; load4(Add + (size_t)gm*addStride + gn, a4);
        r0 += a4[0]; r1 += a4[1]; r2 += a4[2]; r3 += a4[3];
      }
      if (act == 1) { r0 = siluf_(r0); r1 = siluf_(r1); r2 = siluf_(r2); r3 = siluf_(r3); }
      store4(C + (size_t)gm*N + gn, r0, r1, r2, r3);
    }
  }
}

// ---------------------------------------------------------------------------
// Attention scores + softmax. Block = (b,n, i-half): 64 q-rows x 128 k-cols.
// z = silu(base[:,512:640]) (bf16); q = z*g0+b0; k = z*g1+b1.
// score = (q.k)/sqrt(Z) + rpb[1023+j-i]; softmax over j; probs (fp32) to d_out.
// LDS exactly 64KB.
// ---------------------------------------------------------------------------
__global__ __launch_bounds__(256) void attn_scores_kernel(
    const bf16_t* __restrict__ base, const float* __restrict__ qkg,
    const float* __restrict__ qkb, const float* __restrict__ rpb,
    float* __restrict__ attn_out)
{
  __shared__ float qs[64][128];
  __shared__ float ks[64][128];
  int blk = blockIdx.x;            // b*16 + n
  int b = blk >> 4, n = blk & 15;
  int ih = blockIdx.y;             // i-half 0/1
  int tid = threadIdx.x;
  {
    int r = tid >> 2, z0 = (tid & 3)*32;
    size_t rowoff = ((size_t)((n*128 + ih*64 + r)*B_DIM + b))*BASE_N + 512;
    const bf16_t* bp = base + rowoff + z0;
    for (int c = 0; c < 4; ++c) {
      float t8[8]; load8(bp + c*8, t8);
      #pragma unroll
      for (int j = 0; j < 8; ++j) {
        int z = z0 + c*8 + j;
        qs[r][z] = fmaf(siluf_(t8[j]), qkg[z], qkb[z]);
      }
    }
  }
  float acc[32];
  #pragma unroll
  for (int a = 0; a < 32; ++a) acc[a] = 0.f;
  int il = tid >> 2;   // local q row 0..63
  int jq = tid & 3;    // j quarter
  for (int jt = 0; jt < 2; ++jt) {
    __syncthreads();   // protect ks reuse (and qs readiness on jt=0)
    {
      int r = tid >> 2, z0 = (tid & 3)*32;
      size_t rowoff = ((size_t)((n*128 + jt*64 + r)*B_DIM + b))*BASE_N + 512;
      const bf16_t* bp = base + rowoff + z0;
      for (int c = 0; c < 4; ++c) {
        float t8[8]; load8(bp + c*8, t8);
        #pragma unroll
        for (int j = 0; j < 8; ++j) {
          int z = z0 + c*8 + j;
          ks[r][z] = fmaf(siluf_(t8[j]), qkg[128+z], qkb[128+z]);
        }
      }
    }
    __syncthreads();
    for (int z = 0; z < 128; ++z) {
      float qv = qs[il][z];
      #pragma unroll
      for (int jj = 0; jj < 16; ++jj)
        acc[jt*16+jj] = fmaf(qv, ks[jq*16+jj][z], acc[jt*16+jj]);
    }
  }
  const float scale = 0.08838834764831845f;  // 1/sqrt(128)
  int i = ih*64 + il;
  float mxv = -1e30f;
  #pragma unroll
  for (int a = 0; a < 32; ++a) {
    int j = (a >> 4)*64 + jq*16 + (a & 15);
    acc[a] = fmaf(acc[a], scale, rpb[1023 + j - i]);
    mxv = fmaxf(mxv, acc[a]);
  }
  mxv = fmaxf(mxv, __shfl_xor(mxv, 1));
  mxv = fmaxf(mxv, __shfl_xor(mxv, 2));
  float s = 0.f;
  #pragma unroll
  for (int a = 0; a < 32; ++a) { acc[a] = __expf(acc[a] - mxv); s += acc[a]; }
  s += __shfl_xor(s, 1);
  s += __shfl_xor(s, 2);
  float inv = 1.f/s;
  size_t o = ((size_t)blk*128 + i)*128;
  #pragma unroll
  for (int a = 0; a < 32; ++a) {
    int j = (a >> 4)*64 + jq*16 + (a & 15);
    attn_out[o + j] = acc[a]*inv;
  }
}

// ---------------------------------------------------------------------------
// hr = (attn @ vc) * silu(r). Batched GEMM M=128,N=1024,K=128 per (b,n).
// attn fp32 (d_out), v bf16, r from base bf16; hr bf16 in (L,B,H) rows l*16+b.
// ---------------------------------------------------------------------------
__global__ __launch_bounds__(256) void attn_apply_kernel(
    const float* __restrict__ attn, const bf16_t* __restrict__ v,
    const bf16_t* __restrict__ base, bf16_t* __restrict__ hr)
{
  __shared__ float As[16][136];
  __shared__ float Ws[16][128];
  int blk = blockIdx.x;            // b*16 + n
  int b = blk >> 4, n = blk & 15;
  int bn = blockIdx.y;             // h tile 0..7
  int tid = threadIdx.x;
  int tx = tid & 15, ty = tid >> 4;
  float acc[8][8] = {};
  const float* Ab = attn + (size_t)blk*128*128;
  int am = tid >> 1, ak = (tid & 1)*8;
  int wk = tid >> 4, wn = (tid & 15)*8;
  for (int k0 = 0; k0 < 128; k0 += 16) {
    float t8[8];
    load8(Ab + (size_t)am*128 + k0 + ak, t8);
    #pragma unroll
    for (int q = 0; q < 8; ++q) As[ak+q][am] = t8[q];
    load8(v + ((size_t)((n*128 + k0 + wk)*B_DIM + b))*H_DIM + bn*128 + wn, t8);
    #pragma unroll
    for (int q = 0; q < 8; ++q) Ws[wk][wn+q] = t8[q];
    __syncthreads();
    #pragma unroll
    for (int kk = 0; kk < 16; ++kk) {
      float a[8], w[8];
      *(float4*)&a[0] = *(const float4*)&As[kk][ty*8];
      *(float4*)&a[4] = *(const float4*)&As[kk][ty*8+4];
      *(float4*)&w[0] = *(const float4*)&Ws[kk][tx*8];
      *(float4*)&w[4] = *(const float4*)&Ws[kk][tx*8+4];
      #pragma unroll
      for (int i = 0; i < 8; ++i)
        #pragma unroll
        for (int j = 0; j < 8; ++j)
          acc[i][j] = fmaf(a[i], w[j], acc[i][j]);
    }
    __syncthreads();
  }
  #pragma unroll
  for (int i = 0; i < 8; ++i) {
    int l = n*128 + ty*8 + i;
    size_t row = (size_t)l*B_DIM + b;
    #pragma unroll
    for (int jj = 0; jj < 8; jj += 4) {
      int h = bn*128 + tx*8 + jj;
      float r4[4]; load4(base + row*BASE_N + 640 + h, r4);
      store4(hr + row*H_DIM + h,
             acc[i][jj+0]*siluf_(r4[0]),
             acc[i][jj+1]*siluf_(r4[1]),
             acc[i][jj+2]*siluf_(r4[2]),
             acc[i][jj+3]*siluf_(r4[3]));
    }
  }
}

// ---------------------------------------------------------------------------
// out = residual + u*(h2 - residual), then RMSNorm * norm_scalar.
// One wave per row; 8 elems/thread.
// ---------------------------------------------------------------------------
__global__ __launch_bounds__(64) void final_kernel(
    const float* __restrict__ x, const bf16_t* __restrict__ h2,
    const bf16_t* __restrict__ base, const float* __restrict__ ns,
    float* __restrict__ out)
{
  int row = blockIdx.x;
  int t = threadIdx.x;
  size_t ro = (size_t)row*D_DIM + t*8;
  float xv[8]; load8(x + ro, xv);
  float hv[8]; load8(h2 + ro, hv);
  float uv[8]; load8(base + (size_t)row*BASE_N + t*8, uv);
  float o[8];
  float ss = 0.f;
  #pragma unroll
  for (int i = 0; i < 8; ++i) {
    float u = sigmoidf_(uv[i]);
    o[i] = xv[i] + u*(hv[i] - xv[i]);
    ss += o[i]*o[i];
  }
  #pragma unroll
  for (int m = 1; m < 64; m <<= 1) ss += __shfl_xor(ss, m);
  float inv = rsqrtf(ss*(1.f/(float)D_DIM) + 1e-6f) * ns[0];
  float4 r0, r1;
  r0.x = o[0]*inv; r0.y = o[1]*inv; r0.z = o[2]*inv; r0.w = o[3]*inv;
  r1.x = o[4]*inv; r1.y = o[5]*inv; r1.z = o[6]*inv; r1.w = o[7]*inv;
  *(float4*)(out + ro) = r0;
  *(float4*)(out + ro + 4) = r1;
}

// ---------------------------------------------------------------------------
extern "C" void kernel_launch(void* const* d_in, const int* in_sizes, int n_in,
                              void* d_out, int out_size, void* d_ws, size_t ws_size,
                              hipStream_t stream)
{
  const float* x     = (const float*)d_in[0];
  const float* delta = (const float*)d_in[1];
  const float* alpha = (const float*)d_in[2];
  const float* beta  = (const float*)d_in[3];
  const float* gamma = (const float*)d_in[4];
  const float* omega = (const float*)d_in[5];
  const float* Wv    = (const float*)d_in[6];
  const float* bv    = (const float*)d_in[7];
  const float* Wmx   = (const float*)d_in[8];
  const float* bmx   = (const float*)d_in[9];
  const float* Wh    = (const float*)d_in[10];
  const float* bh    = (const float*)d_in[11];
  const float* qkg   = (const float*)d_in[12];
  const float* qkb   = (const float*)d_in[13];
  const float* rpb   = (const float*)d_in[14];
  const float* ns    = (const float*)d_in[15];

  float* out  = (float*)d_out;
  float* attn = out + (size_t)ROWS*D_DIM;          // output 1 at 16,777,216 floats

  // Workspace layout (bytes). Total = 310,378,496 B (~296 MB).
  //  [0,            33,554,432)  mx  bf16 (L,B,D)    -> reused as h2 bf16
  //  [33,554,432,  100,663,296)  v   bf16 (L,B,H)
  //  [100,663,296, 243,269,632)  base bf16 (L,B,2176); yf fp32 (67MB) lives
  //                              here during EMA (dead before base GEMM)
  //  [243,269,632, 310,378,496)  hr  bf16 (L,B,H)
  const size_t WS_NEED = 310378496ull;
  if (ws_size < WS_NEED) {
    // Diagnostic guard: insufficient scratch -> leave d_out zeroed (absmax
    // fail, no crash) so the bench reports ws exhaustion instead of aborting.
    return;
  }
  char* wsb = (char*)d_ws;
  bf16_t* mx_bf   = (bf16_t*)(wsb);
  bf16_t* v_bf    = (bf16_t*)(wsb + 33554432ull);
  bf16_t* base_bf = (bf16_t*)(wsb + 100663296ull);
  bf16_t* hr_bf   = (bf16_t*)(wsb + 243269632ull);
  float*  yf      = (float*)(wsb + 100663296ull);
  bf16_t* h2_bf   = mx_bf;   // mx dead after base GEMM

  ema_fwd_kernel<<<32, 256, 0, stream>>>(x, delta, alpha, beta, gamma, yf);
  ema_bwd_kernel<<<32, 256, 0, stream>>>(x, delta, alpha, beta, gamma, omega, yf, mx_bf);
  // v = silu(x @ Wv + bv)
  gemm_kernel<float,float><<<dim3(H_DIM/128, ROWS/128), 256, 0, stream>>>(
      x, Wv, bv, nullptr, 0, v_bf, ROWS, H_DIM, D_DIM, 1);
  // base = mx @ Wmx + bmx (activations applied at consumption)
  gemm_kernel<bf16_t,float><<<dim3(BASE_N/128, ROWS/128), 256, 0, stream>>>(
      mx_bf, Wmx, bmx, nullptr, 0, base_bf, ROWS, BASE_N, D_DIM, 0);
  // attn probs -> d_out (output 1)
  attn_scores_kernel<<<dim3(B_DIM*NC, 2), 256, 0, stream>>>(base_bf, qkg, qkb, rpb, attn);
  // hr = (attn @ vc) * silu(r)
  attn_apply_kernel<<<dim3(B_DIM*NC, H_DIM/128), 256, 0, stream>>>(attn, v_bf, base_bf, hr_bf);
  // h2 = silu(hx + hr @ Wh + bh)
  gemm_kernel<bf16_t,float><<<dim3(D_DIM/128, ROWS/128), 256, 0, stream>>>(
      hr_bf, Wh, bh, base_bf + 1664, BASE_N, h2_bf, ROWS, D_DIM, H_DIM, 1);
  // gated residual + RMSNorm
  final_kernel<<<ROWS, 64, 0, stream>>>(x, h2_bf, base_bf, ns, out);
}

// Round 3
// 781.714 us; speedup vs baseline: 3.4000x; 3.4000x over previous
//
#include <hip/hip_runtime.h>
#include <math.h>

// Problem dims
#define L_DIM 2048
#define B_DIM 16
#define D_DIM 512
#define H_DIM 1024
#define Z_DIM 128
#define NC    16
#define BASE_N 2176            // Z + H + 2D
#define ROWS  (L_DIM*B_DIM)    // 32768
#define NSEG  16
#define SLEN  128

typedef unsigned short bf16_t;
typedef __attribute__((ext_vector_type(8))) short short8;
typedef __attribute__((ext_vector_type(4))) float f32x4;

__device__ __forceinline__ float sigmoidf_(float x){ return 1.f/(1.f+__expf(-x)); }
__device__ __forceinline__ float siluf_(float x){ return x/(1.f+__expf(-x)); }
__device__ __forceinline__ float fbits(unsigned int b){ union{unsigned int i; float f;} c; c.i=b; return c.f; }
__device__ __forceinline__ unsigned short f2bf(float f){
  union{float f; unsigned int i;} c; c.f=f;
  unsigned int r = c.i + 0x7FFFu + ((c.i>>16)&1u);   // RNE
  return (unsigned short)(r>>16);
}
__device__ __forceinline__ float bf2f(unsigned short u){ return fbits(((unsigned int)u)<<16); }

__device__ __forceinline__ void load8(const float* __restrict__ p, float* d){
  float4 a = *(const float4*)p; float4 b = *(const float4*)(p+4);
  d[0]=a.x; d[1]=a.y; d[2]=a.z; d[3]=a.w; d[4]=b.x; d[5]=b.y; d[6]=b.z; d[7]=b.w;
}
__device__ __forceinline__ void load8(const bf16_t* __restrict__ p, float* d){
  uint4 u = *(const uint4*)p;
  d[0]=fbits(u.x<<16); d[1]=fbits(u.x&0xFFFF0000u);
  d[2]=fbits(u.y<<16); d[3]=fbits(u.y&0xFFFF0000u);
  d[4]=fbits(u.z<<16); d[5]=fbits(u.z&0xFFFF0000u);
  d[6]=fbits(u.w<<16); d[7]=fbits(u.w&0xFFFF0000u);
}
__device__ __forceinline__ void load4(const bf16_t* __restrict__ p, float* d){
  uint2 u = *(const uint2*)p;
  d[0]=fbits(u.x<<16); d[1]=fbits(u.x&0xFFFF0000u);
  d[2]=fbits(u.y<<16); d[3]=fbits(u.y&0xFFFF0000u);
}
__device__ __forceinline__ void store4(bf16_t* p, float a, float b, float c, float dd){
  uint2 s; s.x = (unsigned int)f2bf(a) | ((unsigned int)f2bf(b)<<16);
  s.y = (unsigned int)f2bf(c) | ((unsigned int)f2bf(dd)<<16);
  *(uint2*)p = s;
}
__device__ __forceinline__ void store8bf(bf16_t* p, const float* v){
  uint4 s;
  s.x = (unsigned int)f2bf(v[0]) | ((unsigned int)f2bf(v[1])<<16);
  s.y = (unsigned int)f2bf(v[2]) | ((unsigned int)f2bf(v[3])<<16);
  s.z = (unsigned int)f2bf(v[4]) | ((unsigned int)f2bf(v[5])<<16);
  s.w = (unsigned int)f2bf(v[6]) | ((unsigned int)f2bf(v[7])<<16);
  *(uint4*)p = s;
}

// async global(16B/lane) -> LDS, wave-uniform LDS base + lane*16
__device__ __forceinline__ void glds16(const void* g, void* l) {
  __builtin_amdgcn_global_load_lds(
      (const __attribute__((address_space(1))) unsigned int*)g,
      (__attribute__((address_space(3))) unsigned int*)l, 16, 0, 0);
}

// ---------------------------------------------------------------------------
// fp32 -> bf16 copy (x)
// ---------------------------------------------------------------------------
__global__ __launch_bounds__(256) void cvt_x_kernel(
    const float* __restrict__ x, bf16_t* __restrict__ xb, int n)
{
  int i = (blockIdx.x*256 + threadIdx.x)*4;
  if (i < n) {
    float4 v = *(const float4*)(x + i);
    store4(xb + i, v.x, v.y, v.z, v.w);
  }
}

// ---------------------------------------------------------------------------
// W (K x N fp32) -> Wt (N x K bf16)
// ---------------------------------------------------------------------------
__global__ __launch_bounds__(256) void transpose_cvt_kernel(
    const float* __restrict__ W, bf16_t* __restrict__ Wt, int K, int N)
{
  __shared__ float t[32][33];
  int bx = blockIdx.x, by = blockIdx.y;
  int lx = threadIdx.x & 31, ly = threadIdx.x >> 5;   // 8 rows/iter
  #pragma unroll
  for (int i = 0; i < 32; i += 8)
    t[ly+i][lx] = W[(size_t)(by*32+ly+i)*N + bx*32 + lx];
  __syncthreads();
  #pragma unroll
  for (int i = 0; i < 32; i += 8)
    Wt[(size_t)(bx*32+ly+i)*K + by*32 + lx] = f2bf(t[lx][ly+i]);
}

// ---------------------------------------------------------------------------
// EMA segmented scan. Chains c = b*512+d (8192), 16 segments of 128.
// carry layout: cf0,cf1,cb0,cb1 each [NSEG][8192] fp32.
// ---------------------------------------------------------------------------
__global__ __launch_bounds__(256) void ema_carry_kernel(
    const float* __restrict__ x, const float* __restrict__ delta,
    const float* __restrict__ alpha, float* __restrict__ carry)
{
  int idx = blockIdx.x*256 + threadIdx.x;      // 0..131071
  int d = idx & 511, c = idx & 8191, s = idx >> 13;
  float qf0 = 1.f - sigmoidf_(delta[d*2+0])*sigmoidf_(alpha[d*2+0]);
  float qf1 = 1.f - sigmoidf_(delta[d*2+1])*sigmoidf_(alpha[d*2+1]);
  int dd = d + 512;
  float qb0 = 1.f - sigmoidf_(delta[dd*2+0])*sigmoidf_(alpha[dd*2+0]);
  float qb1 = 1.f - sigmoidf_(delta[dd*2+1])*sigmoidf_(alpha[dd*2+1]);
  const float* xs = x + (size_t)s*SLEN*8192 + (c & 8191) - d + d;  // = base
  size_t off = (size_t)s*SLEN*8192 + c;
  float h0=0.f, h1=0.f;
  for (int t = 0; t < SLEN; ++t) {
    float xv = x[off + (size_t)t*8192];
    h0 = fmaf(qf0, h0, xv); h1 = fmaf(qf1, h1, xv);
  }
  float g0=0.f, g1=0.f;
  for (int t = SLEN-1; t >= 0; --t) {
    float xv = x[off + (size_t)t*8192];
    g0 = fmaf(qb0, g0, xv); g1 = fmaf(qb1, g1, xv);
  }
  carry[(size_t)s*8192 + c]              = h0;
  carry[(size_t)s*8192 + c + 131072]     = h1;
  carry[(size_t)s*8192 + c + 262144]     = g0;
  carry[(size_t)s*8192 + c + 393216]     = g1;
  (void)xs;
}

__global__ __launch_bounds__(256) void ema_combine_kernel(
    const float* __restrict__ delta, const float* __restrict__ alpha,
    float* __restrict__ carry)
{
  int c = blockIdx.x*256 + threadIdx.x;   // 0..8191
  int d = c & 511;
  float qf0 = 1.f - sigmoidf_(delta[d*2+0])*sigmoidf_(alpha[d*2+0]);
  float qf1 = 1.f - sigmoidf_(delta[d*2+1])*sigmoidf_(alpha[d*2+1]);
  int dd = d + 512;
  float qb0 = 1.f - sigmoidf_(delta[dd*2+0])*sigmoidf_(alpha[dd*2+0]);
  float qb1 = 1.f - sigmoidf_(delta[dd*2+1])*sigmoidf_(alpha[dd*2+1]);
  float df0=qf0, df1=qf1, db0=qb0, db1=qb1;
  #pragma unroll
  for (int i = 0; i < 6; ++i) { df0*=df0; df1*=df1; db0*=db0; db1*=db1; }
  df0*=df0; df1*=df1; db0*=db0; db1*=db1;   // q^128
  float h0=0.f, h1=0.f;
  for (int s = 0; s < NSEG; ++s) {
    size_t a = (size_t)s*8192 + c;
    float t0 = carry[a], t1 = carry[a+131072];
    carry[a] = h0; carry[a+131072] = h1;        // init state at segment start
    h0 = fmaf(df0, h0, t0); h1 = fmaf(df1, h1, t1);
  }
  float g0=0.f, g1=0.f;
  for (int s = NSEG-1; s >= 0; --s) {
    size_t a = (size_t)s*8192 + c;
    float t0 = carry[a+262144], t1 = carry[a+393216];
    carry[a+262144] = g0; carry[a+393216] = g1; // init state after segment end
    g0 = fmaf(db0, g0, t0); g1 = fmaf(db1, g1, t1);
  }
}

__global__ __launch_bounds__(256) void ema_apply_kernel(
    const float* __restrict__ x, const float* __restrict__ delta,
    const float* __restrict__ alpha, const float* __restrict__ beta,
    const float* __restrict__ gamma, const float* __restrict__ omega,
    const float* __restrict__ carry, float* __restrict__ yf,
    bf16_t* __restrict__ mx)
{
  int idx = blockIdx.x*256 + threadIdx.x;
  int d = idx & 511, c = idx & 8191, s = idx >> 13;
  const float rs = 0.70710678118654752f;
  float pf0 = sigmoidf_(delta[d*2+0]), pf1 = sigmoidf_(delta[d*2+1]);
  float qf0 = 1.f - pf0*sigmoidf_(alpha[d*2+0]);
  float qf1 = 1.f - pf1*sigmoidf_(alpha[d*2+1]);
  float cf0 = pf0*beta[d*2+0]*gamma[d*2+0]*rs;
  float cf1 = pf1*beta[d*2+1]*gamma[d*2+1]*rs;
  int dd = d + 512;
  float pb0 = sigmoidf_(delta[dd*2+0]), pb1 = sigmoidf_(delta[dd*2+1]);
  float qb0 = 1.f - pb0*sigmoidf_(alpha[dd*2+0]);
  float qb1 = 1.f - pb1*sigmoidf_(alpha[dd*2+1]);
  float cb0 = pb0*beta[dd*2+0]*gamma[dd*2+0]*rs;
  float cb1 = pb1*beta[dd*2+1]*gamma[dd*2+1]*rs;
  float om = omega[d];
  size_t off = (size_t)s*SLEN*8192 + c;
  float h0 = carry[(size_t)s*8192 + c];
  float h1 = carry[(size_t)s*8192 + c + 131072];
  for (int t = 0; t < SLEN; ++t) {
    float xv = x[off + (size_t)t*8192];
    h0 = fmaf(qf0, h0, xv); h1 = fmaf(qf1, h1, xv);
    yf[off + (size_t)t*8192] = fmaf(cf0, h0, cf1*h1);
  }
  float g0 = carry[(size_t)s*8192 + c + 262144];
  float g1 = carry[(size_t)s*8192 + c + 393216];
  for (int t = SLEN-1; t >= 0; --t) {
    size_t a = off + (size_t)t*8192;
    float xv = x[a];
    g0 = fmaf(qb0, g0, xv); g1 = fmaf(qb1, g1, xv);
    float sv = yf[a] + fmaf(cb0, g0, cb1*g1) + xv*om;
    mx[a] = f2bf(siluf_(sv));
  }
}

// ---------------------------------------------------------------------------
// MFMA bf16 GEMM: C(bf16, MxN) = act(A(bf16, MxK) @ Bt^T + bias [+ Add])
// Bt is N x K row-major. 128x128 tile, BK=32, 4 waves (2x2 of 64x64).
// global_load_lds width 16; LDS [row][32] bf16, unpadded (required by glds).
// ---------------------------------------------------------------------------
__global__ __launch_bounds__(256) void mfma_gemm_kernel(
    const bf16_t* __restrict__ A, const bf16_t* __restrict__ Bt,
    const float* __restrict__ bias, const bf16_t* __restrict__ Add, int addLd,
    bf16_t* __restrict__ C, int M, int N, int K, int act)
{
  __shared__ bf16_t As[128*32];
  __shared__ bf16_t Bs[128*32];
  int tid = threadIdx.x;
  int wave = tid >> 6, lane = tid & 63;
  int n0 = blockIdx.x*128, m0 = blockIdx.y*128;
  int srow = lane >> 2, schunk = lane & 3;
  const bf16_t* Ag0 = A + (size_t)(m0 + wave*16 + srow)*K + schunk*8;
  const bf16_t* Ag1 = Ag0 + (size_t)64*K;
  const bf16_t* Bg0 = Bt + (size_t)(n0 + wave*16 + srow)*K + schunk*8;
  const bf16_t* Bg1 = Bg0 + (size_t)64*K;
  bf16_t* Asl0 = As + (wave*16)*32;
  bf16_t* Asl1 = As + (64 + wave*16)*32;
  bf16_t* Bsl0 = Bs + (wave*16)*32;
  bf16_t* Bsl1 = Bs + (64 + wave*16)*32;

  int wm = wave >> 1, wn = wave & 1;
  int fr = lane & 15, fq = lane >> 4;
  f32x4 acc[4][4];
  #pragma unroll
  for (int i = 0; i < 4; ++i)
    #pragma unroll
    for (int j = 0; j < 4; ++j)
      acc[i][j] = (f32x4){0.f,0.f,0.f,0.f};

  for (int k0 = 0; k0 < K; k0 += 32) {
    __syncthreads();
    glds16(Ag0 + k0, Asl0);
    glds16(Ag1 + k0, Asl1);
    glds16(Bg0 + k0, Bsl0);
    glds16(Bg1 + k0, Bsl1);
    __syncthreads();
    short8 af[4], bfr[4];
    #pragma unroll
    for (int mi = 0; mi < 4; ++mi)
      af[mi] = *(const short8*)&As[(wm*64 + mi*16 + fr)*32 + fq*8];
    #pragma unroll
    for (int ni = 0; ni < 4; ++ni)
      bfr[ni] = *(const short8*)&Bs[(wn*64 + ni*16 + fr)*32 + fq*8];
    #pragma unroll
    for (int mi = 0; mi < 4; ++mi)
      #pragma unroll
      for (int ni = 0; ni < 4; ++ni)
        acc[mi][ni] = __builtin_amdgcn_mfma_f32_16x16x32_bf16(
            af[mi], bfr[ni], acc[mi][ni], 0, 0, 0);
  }

  #pragma unroll
  for (int ni = 0; ni < 4; ++ni) {
    int gn = n0 + wn*64 + ni*16 + fr;
    float bv = bias[gn];
    #pragma unroll
    for (int mi = 0; mi < 4; ++mi) {
      #pragma unroll
      for (int r = 0; r < 4; ++r) {
        int gm = m0 + wm*64 + mi*16 + fq*4 + r;
        float val = acc[mi][ni][r] + bv;
        if (Add) val += bf2f(Add[(size_t)gm*addLd + gn]);
        if (act == 1) val = siluf_(val);
        C[(size_t)gm*N + gn] = f2bf(val);
      }
    }
  }
}

// ---------------------------------------------------------------------------
// Attention scores via MFMA + softmax. One block per (b,n): S=128x128 over Z=128.
// q/k staged as bf16 in LDS, row stride 136 (272B = 17*16B: 16B-aligned frags,
// bank stride 4 -> <=2-way conflicts). Probs fp32 -> d_out.
// ---------------------------------------------------------------------------
__global__ __launch_bounds__(256) void attn_scores_mfma_kernel(
    const bf16_t* __restrict__ base, const float* __restrict__ qkg,
    const float* __restrict__ qkb, const float* __restrict__ rpb,
    float* __restrict__ attn_out)
{
  __shared__ bf16_t qs[128*136];
  __shared__ bf16_t ks[128*136];
  int blk = blockIdx.x;            // b*16 + n
  int b = blk >> 4, n = blk & 15;
  int tid = threadIdx.x;
  {
    int r = tid >> 1, z0 = (tid & 1)*64;
    size_t rowoff = ((size_t)((n*128 + r)*B_DIM + b))*BASE_N + 512 + z0;
    #pragma unroll
    for (int cchunk = 0; cchunk < 8; ++cchunk) {
      float t8[8], qv[8], kv[8];
      load8(base + rowoff + cchunk*8, t8);
      #pragma unroll
      for (int j = 0; j < 8; ++j) {
        int z = z0 + cchunk*8 + j;
        float zs = siluf_(t8[j]);
        qv[j] = fmaf(zs, qkg[z],     qkb[z]);
        kv[j] = fmaf(zs, qkg[128+z], qkb[128+z]);
      }
      store8bf(&qs[r*136 + z0 + cchunk*8], qv);
      store8bf(&ks[r*136 + z0 + cchunk*8], kv);
    }
  }
  __syncthreads();
  int wave = tid >> 6, lane = tid & 63;
  int fr = lane & 15, fq = lane >> 4;
  f32x4 acc[2][8];
  #pragma unroll
  for (int i = 0; i < 2; ++i)
    #pragma unroll
    for (int j = 0; j < 8; ++j)
      acc[i][j] = (f32x4){0.f,0.f,0.f,0.f};
  #pragma unroll
  for (int kk = 0; kk < 4; ++kk) {
    short8 af[2], bfr[8];
    #pragma unroll
    for (int mi = 0; mi < 2; ++mi)
      af[mi] = *(const short8*)&qs[(wave*32 + mi*16 + fr)*136 + kk*32 + fq*8];
    #pragma unroll
    for (int ni = 0; ni < 8; ++ni)
      bfr[ni] = *(const short8*)&ks[(ni*16 + fr)*136 + kk*32 + fq*8];
    #pragma unroll
    for (int mi = 0; mi < 2; ++mi)
      #pragma unroll
      for (int ni = 0; ni < 8; ++ni)
        acc[mi][ni] = __builtin_amdgcn_mfma_f32_16x16x32_bf16(
            af[mi], bfr[ni], acc[mi][ni], 0, 0, 0);
  }
  // softmax over j (cols). Row i = wave*32+mi*16+fq*4+r; col j = ni*16+fr.
  const float scale = 0.08838834764831845f;  // 1/sqrt(128)
  float mrow[2][4], srow[2][4];
  #pragma unroll
  for (int mi = 0; mi < 2; ++mi)
    #pragma unroll
    for (int r = 0; r < 4; ++r) mrow[mi][r] = -1e30f;
  #pragma unroll
  for (int mi = 0; mi < 2; ++mi)
    #pragma unroll
    for (int ni = 0; ni < 8; ++ni)
      #pragma unroll
      for (int r = 0; r < 4; ++r) {
        int i = wave*32 + mi*16 + fq*4 + r;
        int j = ni*16 + fr;
        float v = fmaf(acc[mi][ni][r], scale, rpb[1023 + j - i]);
        acc[mi][ni][r] = v;
        mrow[mi][r] = fmaxf(mrow[mi][r], v);
      }
  #pragma unroll
  for (int mi = 0; mi < 2; ++mi)
    #pragma unroll
    for (int r = 0; r < 4; ++r) {
      float m = mrow[mi][r];
      m = fmaxf(m, __shfl_xor(m, 1));
      m = fmaxf(m, __shfl_xor(m, 2));
      m = fmaxf(m, __shfl_xor(m, 4));
      m = fmaxf(m, __shfl_xor(m, 8));
      mrow[mi][r] = m;
      srow[mi][r] = 0.f;
    }
  #pragma unroll
  for (int mi = 0; mi < 2; ++mi)
    #pragma unroll
    for (int ni = 0; ni < 8; ++ni)
      #pragma unroll
      for (int r = 0; r < 4; ++r) {
        float e = __expf(acc[mi][ni][r] - mrow[mi][r]);
        acc[mi][ni][r] = e;
        srow[mi][r] += e;
      }
  #pragma unroll
  for (int mi = 0; mi < 2; ++mi)
    #pragma unroll
    for (int r = 0; r < 4; ++r) {
      float s = srow[mi][r];
      s += __shfl_xor(s, 1);
      s += __shfl_xor(s, 2);
      s += __shfl_xor(s, 4);
      s += __shfl_xor(s, 8);
      srow[mi][r] = 1.f/s;
    }
  #pragma unroll
  for (int mi = 0; mi < 2; ++mi)
    #pragma unroll
    for (int r = 0; r < 4; ++r) {
      int i = wave*32 + mi*16 + fq*4 + r;
      size_t o = ((size_t)blk*128 + i)*128;
      #pragma unroll
      for (int ni = 0; ni < 8; ++ni)
        attn_out[o + ni*16 + fr] = acc[mi][ni][r]*srow[mi][r];
    }
}

// ---------------------------------------------------------------------------
// hr = (attn @ vc) * silu(r). fp32 VALU batched GEMM (small share of runtime).
// ---------------------------------------------------------------------------
__global__ __launch_bounds__(256) void attn_apply_kernel(
    const float* __restrict__ attn, const bf16_t* __restrict__ v,
    const bf16_t* __restrict__ base, bf16_t* __restrict__ hr)
{
  __shared__ float As[16][136];
  __shared__ float Ws[16][128];
  int blk = blockIdx.x;            // b*16 + n
  int b = blk >> 4, n = blk & 15;
  int bn = blockIdx.y;             // h tile 0..7
  int tid = threadIdx.x;
  int tx = tid & 15, ty = tid >> 4;
  float acc[8][8] = {};
  const float* Ab = attn + (size_t)blk*128*128;
  int am = tid >> 1, ak = (tid & 1)*8;
  int wk = tid >> 4, wn = (tid & 15)*8;
  for (int k0 = 0; k0 < 128; k0 += 16) {
    float t8[8];
    load8(Ab + (size_t)am*128 + k0 + ak, t8);
    #pragma unroll
    for (int q = 0; q < 8; ++q) As[ak+q][am] = t8[q];
    load8(v + ((size_t)((n*128 + k0 + wk)*B_DIM + b))*H_DIM + bn*128 + wn, t8);
    #pragma unroll
    for (int q = 0; q < 8; ++q) Ws[wk][wn+q] = t8[q];
    __syncthreads();
    #pragma unroll
    for (int kk = 0; kk < 16; ++kk) {
      float a[8], w[8];
      *(float4*)&a[0] = *(const float4*)&As[kk][ty*8];
      *(float4*)&a[4] = *(const float4*)&As[kk][ty*8+4];
      *(float4*)&w[0] = *(const float4*)&Ws[kk][tx*8];
      *(float4*)&w[4] = *(const float4*)&Ws[kk][tx*8+4];
      #pragma unroll
      for (int i = 0; i < 8; ++i)
        #pragma unroll
        for (int j = 0; j < 8; ++j)
          acc[i][j] = fmaf(a[i], w[j], acc[i][j]);
    }
    __syncthreads();
  }
  #pragma unroll
  for (int i = 0; i < 8; ++i) {
    int l = n*128 + ty*8 + i;
    size_t row = (size_t)l*B_DIM + b;
    #pragma unroll
    for (int jj = 0; jj < 8; jj += 4) {
      int h = bn*128 + tx*8 + jj;
      float r4[4]; load4(base + row*BASE_N + 640 + h, r4);
      store4(hr + row*H_DIM + h,
             acc[i][jj+0]*siluf_(r4[0]),
             acc[i][jj+1]*siluf_(r4[1]),
             acc[i][jj+2]*siluf_(r4[2]),
             acc[i][jj+3]*siluf_(r4[3]));
    }
  }
}

// ---------------------------------------------------------------------------
// out = residual + u*(h2 - residual), then RMSNorm * norm_scalar.
// ---------------------------------------------------------------------------
__global__ __launch_bounds__(64) void final_kernel(
    const float* __restrict__ x, const bf16_t* __restrict__ h2,
    const bf16_t* __restrict__ base, const float* __restrict__ ns,
    float* __restrict__ out)
{
  int row = blockIdx.x;
  int t = threadIdx.x;
  size_t ro = (size_t)row*D_DIM + t*8;
  float xv[8]; load8(x + ro, xv);
  float hv[8]; load8(h2 + ro, hv);
  float uv[8]; load8(base + (size_t)row*BASE_N + t*8, uv);
  float o[8];
  float ss = 0.f;
  #pragma unroll
  for (int i = 0; i < 8; ++i) {
    float u = sigmoidf_(uv[i]);
    o[i] = xv[i] + u*(hv[i] - xv[i]);
    ss += o[i]*o[i];
  }
  #pragma unroll
  for (int m = 1; m < 64; m <<= 1) ss += __shfl_xor(ss, m);
  float inv = rsqrtf(ss*(1.f/(float)D_DIM) + 1e-6f) * ns[0];
  float4 r0, r1;
  r0.x = o[0]*inv; r0.y = o[1]*inv; r0.z = o[2]*inv; r0.w = o[3]*inv;
  r1.x = o[4]*inv; r1.y = o[5]*inv; r1.z = o[6]*inv; r1.w = o[7]*inv;
  *(float4*)(out + ro) = r0;
  *(float4*)(out + ro + 4) = r1;
}

// ---------------------------------------------------------------------------
extern "C" void kernel_launch(void* const* d_in, const int* in_sizes, int n_in,
                              void* d_out, int out_size, void* d_ws, size_t ws_size,
                              hipStream_t stream)
{
  const float* x     = (const float*)d_in[0];
  const float* delta = (const float*)d_in[1];
  const float* alpha = (const float*)d_in[2];
  const float* beta  = (const float*)d_in[3];
  const float* gamma = (const float*)d_in[4];
  const float* omega = (const float*)d_in[5];
  const float* Wv    = (const float*)d_in[6];
  const float* bv    = (const float*)d_in[7];
  const float* Wmx   = (const float*)d_in[8];
  const float* bmx   = (const float*)d_in[9];
  const float* Wh    = (const float*)d_in[10];
  const float* bh    = (const float*)d_in[11];
  const float* qkg   = (const float*)d_in[12];
  const float* qkb   = (const float*)d_in[13];
  const float* rpb   = (const float*)d_in[14];
  const float* ns    = (const float*)d_in[15];

  float* out  = (float*)d_out;
  float* attn = out + (size_t)ROWS*D_DIM;          // bytes [67,108,864, 83,886,080)

  // d_out out-area doubles as scratch until final_kernel (bytes [0, 67,108,864)):
  //   x_bf  [0,          33,554,432)
  //   Wv_t  [33,554,432, 34,603,008)   1024x512 bf16
  //   Wmx_t [34,603,008, 36,831,232)   2176x512 bf16
  //   Wh_t  [36,831,232, 37,879,808)   512x1024 bf16
  char* outb = (char*)d_out;
  bf16_t* x_bf  = (bf16_t*)outb;
  bf16_t* Wv_t  = (bf16_t*)(outb + 33554432ull);
  bf16_t* Wmx_t = (bf16_t*)(outb + 34603008ull);
  bf16_t* Wh_t  = (bf16_t*)(outb + 36831232ull);

  // Workspace (>= 310,378,496 B, verified round 2):
  //  [0,            33,554,432)  mx bf16  -> later h2 bf16
  //  [33,554,432,  100,663,296)  v  bf16
  //  [100,663,296, 243,269,632)  base bf16; during EMA: yf fp32 (134,217,728)
  //                              + carries (2,097,152) at +134,217,728
  //  [243,269,632, 310,378,496)  hr bf16
  const size_t WS_NEED = 310378496ull;
  if (ws_size < WS_NEED) return;
  char* wsb = (char*)d_ws;
  bf16_t* mx_bf   = (bf16_t*)(wsb);
  bf16_t* v_bf    = (bf16_t*)(wsb + 33554432ull);
  bf16_t* base_bf = (bf16_t*)(wsb + 100663296ull);
  bf16_t* hr_bf   = (bf16_t*)(wsb + 243269632ull);
  float*  yf      = (float*)(wsb + 100663296ull);
  float*  carry   = (float*)(wsb + 100663296ull + 134217728ull);
  bf16_t* h2_bf   = mx_bf;

  // conversions
  cvt_x_kernel<<<16384, 256, 0, stream>>>(x, x_bf, ROWS*D_DIM);
  transpose_cvt_kernel<<<dim3(32, 16), 256, 0, stream>>>(Wv,  Wv_t,  512, 1024);
  transpose_cvt_kernel<<<dim3(68, 16), 256, 0, stream>>>(Wmx, Wmx_t, 512, 2176);
  transpose_cvt_kernel<<<dim3(16, 32), 256, 0, stream>>>(Wh,  Wh_t,  1024, 512);
  // EMA segmented scan -> mx
  ema_carry_kernel<<<512, 256, 0, stream>>>(x, delta, alpha, carry);
  ema_combine_kernel<<<32, 256, 0, stream>>>(delta, alpha, carry);
  ema_apply_kernel<<<512, 256, 0, stream>>>(x, delta, alpha, beta, gamma, omega,
                                            carry, yf, mx_bf);
  // v = silu(x @ Wv + bv)
  mfma_gemm_kernel<<<dim3(H_DIM/128, ROWS/128), 256, 0, stream>>>(
      x_bf, Wv_t, bv, nullptr, 0, v_bf, ROWS, H_DIM, D_DIM, 1);
  // base = mx @ Wmx + bmx
  mfma_gemm_kernel<<<dim3(BASE_N/128, ROWS/128), 256, 0, stream>>>(
      mx_bf, Wmx_t, bmx, nullptr, 0, base_bf, ROWS, BASE_N, D_DIM, 0);
  // attn probs (fp32) -> d_out
  attn_scores_mfma_kernel<<<B_DIM*NC, 256, 0, stream>>>(base_bf, qkg, qkb, rpb, attn);
  // hr = (attn @ vc) * silu(r)
  attn_apply_kernel<<<dim3(B_DIM*NC, H_DIM/128), 256, 0, stream>>>(attn, v_bf, base_bf, hr_bf);
  // h2 = silu(hx + hr @ Wh + bh)
  mfma_gemm_kernel<<<dim3(D_DIM/128, ROWS/128), 256, 0, stream>>>(
      hr_bf, Wh_t, bh, base_bf + 1664, BASE_N, h2_bf, ROWS, D_DIM, H_DIM, 1);
  // gated residual + RMSNorm
  final_kernel<<<ROWS, 64, 0, stream>>>(x, h2_bf, base_bf, ns, out);
}

// Round 4
// 678.529 us; speedup vs baseline: 3.9170x; 1.1521x over previous
//
#include <hip/hip_runtime.h>
#include <math.h>

// Problem dims
#define L_DIM 2048
#define B_DIM 16
#define D_DIM 512
#define H_DIM 1024
#define Z_DIM 128
#define NC    16
#define BASE_N 2176            // Z + H + 2D
#define ROWS  (L_DIM*B_DIM)    // 32768
#define NSEG  32
#define SLEN  64
#define CHAINS 8192            // B*D

typedef unsigned short bf16_t;
typedef __attribute__((ext_vector_type(8))) short short8;
typedef __attribute__((ext_vector_type(4))) float f32x4;

__device__ __forceinline__ float sigmoidf_(float x){ return 1.f/(1.f+__expf(-x)); }
__device__ __forceinline__ float siluf_(float x){ return x/(1.f+__expf(-x)); }
__device__ __forceinline__ float fbits(unsigned int b){ union{unsigned int i; float f;} c; c.i=b; return c.f; }
__device__ __forceinline__ unsigned short f2bf(float f){
  union{float f; unsigned int i;} c; c.f=f;
  unsigned int r = c.i + 0x7FFFu + ((c.i>>16)&1u);   // RNE
  return (unsigned short)(r>>16);
}
__device__ __forceinline__ float bf2f(unsigned short u){ return fbits(((unsigned int)u)<<16); }

__device__ __forceinline__ void load8(const float* __restrict__ p, float* d){
  float4 a = *(const float4*)p; float4 b = *(const float4*)(p+4);
  d[0]=a.x; d[1]=a.y; d[2]=a.z; d[3]=a.w; d[4]=b.x; d[5]=b.y; d[6]=b.z; d[7]=b.w;
}
__device__ __forceinline__ void load8(const bf16_t* __restrict__ p, float* d){
  uint4 u = *(const uint4*)p;
  d[0]=fbits(u.x<<16); d[1]=fbits(u.x&0xFFFF0000u);
  d[2]=fbits(u.y<<16); d[3]=fbits(u.y&0xFFFF0000u);
  d[4]=fbits(u.z<<16); d[5]=fbits(u.z&0xFFFF0000u);
  d[6]=fbits(u.w<<16); d[7]=fbits(u.w&0xFFFF0000u);
}
__device__ __forceinline__ void store8bf(bf16_t* p, const float* v){
  uint4 s;
  s.x = (unsigned int)f2bf(v[0]) | ((unsigned int)f2bf(v[1])<<16);
  s.y = (unsigned int)f2bf(v[2]) | ((unsigned int)f2bf(v[3])<<16);
  s.z = (unsigned int)f2bf(v[4]) | ((unsigned int)f2bf(v[5])<<16);
  s.w = (unsigned int)f2bf(v[6]) | ((unsigned int)f2bf(v[7])<<16);
  *(uint4*)p = s;
}

// async global(16B/lane) -> LDS, wave-uniform LDS base + lane*16
__device__ __forceinline__ void glds16(const void* g, void* l) {
  __builtin_amdgcn_global_load_lds(
      (const __attribute__((address_space(1))) unsigned int*)g,
      (__attribute__((address_space(3))) unsigned int*)l, 16, 0, 0);
}

// ---------------------------------------------------------------------------
// W (K x N fp32) -> Wt (N x K bf16)
// ---------------------------------------------------------------------------
__global__ __launch_bounds__(256) void transpose_cvt_kernel(
    const float* __restrict__ W, bf16_t* __restrict__ Wt, int K, int N)
{
  __shared__ float t[32][33];
  int bx = blockIdx.x, by = blockIdx.y;
  int lx = threadIdx.x & 31, ly = threadIdx.x >> 5;   // 8 rows/iter
  #pragma unroll
  for (int i = 0; i < 32; i += 8)
    t[ly+i][lx] = W[(size_t)(by*32+ly+i)*N + bx*32 + lx];
  __syncthreads();
  #pragma unroll
  for (int i = 0; i < 32; i += 8)
    Wt[(size_t)(bx*32+ly+i)*K + by*32 + lx] = f2bf(t[lx][ly+i]);
}

// ---------------------------------------------------------------------------
// EMA segmented scan, SLEN=64, NSEG=32. Chains c = b*512+d (8192).
// carry layout: cf0,cf1,cb0,cb1 each [NSEG][8192] fp32 (1 MB each).
// carry kernel also produces x_bf (bf16 copy of x) for later GEMM/apply use.
// ---------------------------------------------------------------------------
__global__ __launch_bounds__(256) void ema_carry_kernel(
    const float* __restrict__ x, const float* __restrict__ delta,
    const float* __restrict__ alpha, bf16_t* __restrict__ xb,
    float* __restrict__ carry)
{
  int idx = blockIdx.x*256 + threadIdx.x;      // 0..262143
  int d = idx & 511, c = idx & 8191, s = idx >> 13;   // s in 0..31
  float qf0 = 1.f - sigmoidf_(delta[d*2+0])*sigmoidf_(alpha[d*2+0]);
  float qf1 = 1.f - sigmoidf_(delta[d*2+1])*sigmoidf_(alpha[d*2+1]);
  int dd = d + 512;
  float qb0 = 1.f - sigmoidf_(delta[dd*2+0])*sigmoidf_(alpha[dd*2+0]);
  float qb1 = 1.f - sigmoidf_(delta[dd*2+1])*sigmoidf_(alpha[dd*2+1]);
  size_t off = (size_t)s*SLEN*CHAINS + c;
  float h0=0.f, h1=0.f;
  #pragma unroll
  for (int t = 0; t < SLEN; ++t) {
    size_t a = off + (size_t)t*CHAINS;
    float xv = x[a];
    xb[a] = f2bf(xv);
    h0 = fmaf(qf0, h0, xv); h1 = fmaf(qf1, h1, xv);
  }
  float g0=0.f, g1=0.f;
  #pragma unroll
  for (int t = SLEN-1; t >= 0; --t) {
    float xv = bf2f(xb[off + (size_t)t*CHAINS]);   // L2-hot reread
    g0 = fmaf(qb0, g0, xv); g1 = fmaf(qb1, g1, xv);
  }
  carry[(size_t)s*CHAINS + c]              = h0;
  carry[(size_t)s*CHAINS + c + 262144]     = h1;
  carry[(size_t)s*CHAINS + c + 524288]     = g0;
  carry[(size_t)s*CHAINS + c + 786432]     = g1;
}

__global__ __launch_bounds__(256) void ema_combine_kernel(
    const float* __restrict__ delta, const float* __restrict__ alpha,
    float* __restrict__ carry)
{
  int c = blockIdx.x*256 + threadIdx.x;   // 0..8191
  int d = c & 511;
  float qf0 = 1.f - sigmoidf_(delta[d*2+0])*sigmoidf_(alpha[d*2+0]);
  float qf1 = 1.f - sigmoidf_(delta[d*2+1])*sigmoidf_(alpha[d*2+1]);
  int dd = d + 512;
  float qb0 = 1.f - sigmoidf_(delta[dd*2+0])*sigmoidf_(alpha[dd*2+0]);
  float qb1 = 1.f - sigmoidf_(delta[dd*2+1])*sigmoidf_(alpha[dd*2+1]);
  float df0=qf0, df1=qf1, db0=qb0, db1=qb1;
  #pragma unroll
  for (int i = 0; i < 6; ++i) { df0*=df0; df1*=df1; db0*=db0; db1*=db1; }  // q^64
  float h0=0.f, h1=0.f;
  for (int s = 0; s < NSEG; ++s) {
    size_t a = (size_t)s*CHAINS + c;
    float t0 = carry[a], t1 = carry[a+262144];
    carry[a] = h0; carry[a+262144] = h1;        // state entering segment s
    h0 = fmaf(df0, h0, t0); h1 = fmaf(df1, h1, t1);
  }
  float g0=0.f, g1=0.f;
  for (int s = NSEG-1; s >= 0; --s) {
    size_t a = (size_t)s*CHAINS + c;
    float t0 = carry[a+524288], t1 = carry[a+786432];
    carry[a+524288] = g0; carry[a+786432] = g1; // state entering from right
    g0 = fmaf(db0, g0, t0); g1 = fmaf(db1, g1, t1);
  }
}

__global__ __launch_bounds__(256) void ema_apply_kernel(
    const bf16_t* __restrict__ xb, const float* __restrict__ delta,
    const float* __restrict__ alpha, const float* __restrict__ beta,
    const float* __restrict__ gamma, const float* __restrict__ omega,
    const float* __restrict__ carry, bf16_t* __restrict__ mx)
{
  int idx = blockIdx.x*256 + threadIdx.x;
  int d = idx & 511, c = idx & 8191, s = idx >> 13;
  const float rs = 0.70710678118654752f;
  float pf0 = sigmoidf_(delta[d*2+0]), pf1 = sigmoidf_(delta[d*2+1]);
  float qf0 = 1.f - pf0*sigmoidf_(alpha[d*2+0]);
  float qf1 = 1.f - pf1*sigmoidf_(alpha[d*2+1]);
  float cf0 = pf0*beta[d*2+0]*gamma[d*2+0]*rs;
  float cf1 = pf1*beta[d*2+1]*gamma[d*2+1]*rs;
  int dd = d + 512;
  float pb0 = sigmoidf_(delta[dd*2+0]), pb1 = sigmoidf_(delta[dd*2+1]);
  float qb0 = 1.f - pb0*sigmoidf_(alpha[dd*2+0]);
  float qb1 = 1.f - pb1*sigmoidf_(alpha[dd*2+1]);
  float cb0 = pb0*beta[dd*2+0]*gamma[dd*2+0]*rs;
  float cb1 = pb1*beta[dd*2+1]*gamma[dd*2+1]*rs;
  float om = omega[d];
  size_t off = (size_t)s*SLEN*CHAINS + c;
  float h0 = carry[(size_t)s*CHAINS + c];
  float h1 = carry[(size_t)s*CHAINS + c + 262144];
  float yv[SLEN];                    // fwd partials in registers
  #pragma unroll
  for (int t = 0; t < SLEN; ++t) {
    float xv = bf2f(xb[off + (size_t)t*CHAINS]);
    h0 = fmaf(qf0, h0, xv); h1 = fmaf(qf1, h1, xv);
    yv[t] = fmaf(cf0, h0, cf1*h1);
  }
  float g0 = carry[(size_t)s*CHAINS + c + 524288];
  float g1 = carry[(size_t)s*CHAINS + c + 786432];
  #pragma unroll
  for (int t = SLEN-1; t >= 0; --t) {
    size_t a = off + (size_t)t*CHAINS;
    float xv = bf2f(xb[a]);          // L2-hot reread
    g0 = fmaf(qb0, g0, xv); g1 = fmaf(qb1, g1, xv);
    float sv = yv[t] + fmaf(cb0, g0, cb1*g1) + xv*om;
    mx[a] = f2bf(siluf_(sv));
  }
}

// ---------------------------------------------------------------------------
// Generic MFMA bf16 GEMM: C(bf16, MxN) = act(A @ Bt^T + bias [+ Add])
// Bt is N x K row-major. 128x128 tile, BK=32, 4 waves. 1-D grid, XCD swizzle
// (same m-tile -> same XCD for A-tile L2 reuse). Epilogue repacks the tile
// through LDS and stores dwordx4.
// ---------------------------------------------------------------------------
__global__ __launch_bounds__(256) void mfma_gemm_kernel(
    const bf16_t* __restrict__ A, const bf16_t* __restrict__ Bt,
    const float* __restrict__ bias, const bf16_t* __restrict__ Add, int addLd,
    bf16_t* __restrict__ C, int N, int K, int nT, int act)
{
  __shared__ __align__(16) char smem[34816];
  bf16_t* As = (bf16_t*)smem;            // 128x32
  bf16_t* Bs = (bf16_t*)(smem + 8192);   // 128x32
  bf16_t* Cs = (bf16_t*)smem;            // 128x136 (reuse after K-loop)
  int flat = blockIdx.x;
  int xcd = flat & 7, g = flat >> 3;
  int mT8 = (int)(gridDim.x / (unsigned)nT) >> 3;
  int mt = xcd*mT8 + g / nT;
  int nt = g % nT;
  int m0 = mt*128, n0 = nt*128;
  int tid = threadIdx.x;
  int wave = tid >> 6, lane = tid & 63;
  int srow = lane >> 2, schunk = lane & 3;
  const bf16_t* Ag0 = A + (size_t)(m0 + wave*16 + srow)*K + schunk*8;
  const bf16_t* Ag1 = Ag0 + (size_t)64*K;
  const bf16_t* Bg0 = Bt + (size_t)(n0 + wave*16 + srow)*K + schunk*8;
  const bf16_t* Bg1 = Bg0 + (size_t)64*K;
  bf16_t* Asl0 = As + (wave*16)*32;
  bf16_t* Asl1 = As + (64 + wave*16)*32;
  bf16_t* Bsl0 = Bs + (wave*16)*32;
  bf16_t* Bsl1 = Bs + (64 + wave*16)*32;

  int wm = wave >> 1, wn = wave & 1;
  int fr = lane & 15, fq = lane >> 4;
  f32x4 acc[4][4];
  #pragma unroll
  for (int i = 0; i < 4; ++i)
    #pragma unroll
    for (int j = 0; j < 4; ++j)
      acc[i][j] = (f32x4){0.f,0.f,0.f,0.f};

  for (int k0 = 0; k0 < K; k0 += 32) {
    __syncthreads();
    glds16(Ag0 + k0, Asl0);
    glds16(Ag1 + k0, Asl1);
    glds16(Bg0 + k0, Bsl0);
    glds16(Bg1 + k0, Bsl1);
    __syncthreads();
    short8 af[4], bfr[4];
    #pragma unroll
    for (int mi = 0; mi < 4; ++mi)
      af[mi] = *(const short8*)&As[(wm*64 + mi*16 + fr)*32 + fq*8];
    #pragma unroll
    for (int ni = 0; ni < 4; ++ni)
      bfr[ni] = *(const short8*)&Bs[(wn*64 + ni*16 + fr)*32 + fq*8];
    #pragma unroll
    for (int mi = 0; mi < 4; ++mi)
      #pragma unroll
      for (int ni = 0; ni < 4; ++ni)
        acc[mi][ni] = __builtin_amdgcn_mfma_f32_16x16x32_bf16(
            af[mi], bfr[ni], acc[mi][ni], 0, 0, 0);
  }

  __syncthreads();   // staging LDS reads done; safe to overwrite with Cs
  #pragma unroll
  for (int ni = 0; ni < 4; ++ni) {
    int cl = wn*64 + ni*16 + fr;     // local col
    int gn = n0 + cl;
    float bv = bias[gn];
    #pragma unroll
    for (int mi = 0; mi < 4; ++mi) {
      #pragma unroll
      for (int r = 0; r < 4; ++r) {
        int ml = wm*64 + mi*16 + fq*4 + r;   // local row
        float val = acc[mi][ni][r] + bv;
        if (Add) val += bf2f(Add[(size_t)(m0+ml)*addLd + gn]);
        if (act == 1) val = siluf_(val);
        Cs[ml*136 + cl] = f2bf(val);
      }
    }
  }
  __syncthreads();
  int row = tid >> 1, c0 = (tid & 1)*64;
  #pragma unroll
  for (int q = 0; q < 8; ++q)
    *(uint4*)(C + (size_t)(m0+row)*N + n0 + c0 + q*8) =
        *(const uint4*)&Cs[row*136 + c0 + q*8];
}

// ---------------------------------------------------------------------------
// Wv GEMM variant: vt[b][nchunk][h][k] = silu(x @ Wv + bv), transposed per
// 128-chunk so PV can consume it as an N x K "Bt". N = 1024, K = 512.
// ---------------------------------------------------------------------------
__global__ __launch_bounds__(256) void mfma_gemm_v_kernel(
    const bf16_t* __restrict__ A, const bf16_t* __restrict__ Bt,
    const float* __restrict__ bias, bf16_t* __restrict__ vt, int nT, int K)
{
  __shared__ __align__(16) char smem[34816];
  bf16_t* As = (bf16_t*)smem;
  bf16_t* Bs = (bf16_t*)(smem + 8192);
  bf16_t* Cs = (bf16_t*)smem;
  const int N = H_DIM;
  int flat = blockIdx.x;
  int xcd = flat & 7, g = flat >> 3;
  int mT8 = (int)(gridDim.x / (unsigned)nT) >> 3;
  int mt = xcd*mT8 + g / nT;
  int nt = g % nT;
  int m0 = mt*128, n0 = nt*128;
  int tid = threadIdx.x;
  int wave = tid >> 6, lane = tid & 63;
  int srow = lane >> 2, schunk = lane & 3;
  const bf16_t* Ag0 = A + (size_t)(m0 + wave*16 + srow)*K + schunk*8;
  const bf16_t* Ag1 = Ag0 + (size_t)64*K;
  const bf16_t* Bg0 = Bt + (size_t)(n0 + wave*16 + srow)*K + schunk*8;
  const bf16_t* Bg1 = Bg0 + (size_t)64*K;
  bf16_t* Asl0 = As + (wave*16)*32;
  bf16_t* Asl1 = As + (64 + wave*16)*32;
  bf16_t* Bsl0 = Bs + (wave*16)*32;
  bf16_t* Bsl1 = Bs + (64 + wave*16)*32;

  int wm = wave >> 1, wn = wave & 1;
  int fr = lane & 15, fq = lane >> 4;
  f32x4 acc[4][4];
  #pragma unroll
  for (int i = 0; i < 4; ++i)
    #pragma unroll
    for (int j = 0; j < 4; ++j)
      acc[i][j] = (f32x4){0.f,0.f,0.f,0.f};

  for (int k0 = 0; k0 < K; k0 += 32) {
    __syncthreads();
    glds16(Ag0 + k0, Asl0);
    glds16(Ag1 + k0, Asl1);
    glds16(Bg0 + k0, Bsl0);
    glds16(Bg1 + k0, Bsl1);
    __syncthreads();
    short8 af[4], bfr[4];
    #pragma unroll
    for (int mi = 0; mi < 4; ++mi)
      af[mi] = *(const short8*)&As[(wm*64 + mi*16 + fr)*32 + fq*8];
    #pragma unroll
    for (int ni = 0; ni < 4; ++ni)
      bfr[ni] = *(const short8*)&Bs[(wn*64 + ni*16 + fr)*32 + fq*8];
    #pragma unroll
    for (int mi = 0; mi < 4; ++mi)
      #pragma unroll
      for (int ni = 0; ni < 4; ++ni)
        acc[mi][ni] = __builtin_amdgcn_mfma_f32_16x16x32_bf16(
            af[mi], bfr[ni], acc[mi][ni], 0, 0, 0);
  }

  __syncthreads();
  #pragma unroll
  for (int ni = 0; ni < 4; ++ni) {
    int cl = wn*64 + ni*16 + fr;
    float bv = bias[n0 + cl];
    #pragma unroll
    for (int mi = 0; mi < 4; ++mi) {
      #pragma unroll
      for (int r = 0; r < 4; ++r) {
        int ml = wm*64 + mi*16 + fq*4 + r;
        Cs[ml*136 + cl] = f2bf(siluf_(acc[mi][ni][r] + bv));
      }
    }
  }
  __syncthreads();
  // Tile rows are gm = m0 + (kk*16 + b): l = mt*8 + kk, b = row&15.
  // vt[(b*16 + nchunk)*1024 + h][128 k], nchunk = mt>>4, k = (mt&15)*8 + kk.
  int b = tid >> 4, h0l = (tid & 15)*8;
  int nchunk = mt >> 4, kbase = (mt & 15)*8;
  #pragma unroll
  for (int j = 0; j < 8; ++j) {
    int hl = h0l + j;
    uint4 s;
    unsigned int w0 = (unsigned int)Cs[(0*16 + b)*136 + hl] |
                      ((unsigned int)Cs[(1*16 + b)*136 + hl] << 16);
    unsigned int w1 = (unsigned int)Cs[(2*16 + b)*136 + hl] |
                      ((unsigned int)Cs[(3*16 + b)*136 + hl] << 16);
    unsigned int w2 = (unsigned int)Cs[(4*16 + b)*136 + hl] |
                      ((unsigned int)Cs[(5*16 + b)*136 + hl] << 16);
    unsigned int w3 = (unsigned int)Cs[(6*16 + b)*136 + hl] |
                      ((unsigned int)Cs[(7*16 + b)*136 + hl] << 16);
    s.x=w0; s.y=w1; s.z=w2; s.w=w3;
    *(uint4*)&vt[((size_t)(b*NC + nchunk)*H_DIM + n0 + hl)*128 + kbase] = s;
  }
}

// ---------------------------------------------------------------------------
// Attention scores via MFMA + softmax. One block per (b,n).
// Writes fp32 probs to d_out AND bf16 probs (p_bf) for the PV GEMM.
// ---------------------------------------------------------------------------
__global__ __launch_bounds__(256) void attn_scores_mfma_kernel(
    const bf16_t* __restrict__ base, const float* __restrict__ qkg,
    const float* __restrict__ qkb, const float* __restrict__ rpb,
    float* __restrict__ attn_out, bf16_t* __restrict__ p_bf)
{
  __shared__ bf16_t qs[128*136];
  __shared__ bf16_t ks[128*136];
  int blk = blockIdx.x;            // b*16 + n
  int b = blk >> 4, n = blk & 15;
  int tid = threadIdx.x;
  {
    int r = tid >> 1, z0 = (tid & 1)*64;
    size_t rowoff = ((size_t)((n*128 + r)*B_DIM + b))*BASE_N + 512 + z0;
    #pragma unroll
    for (int cchunk = 0; cchunk < 8; ++cchunk) {
      float t8[8], qv[8], kv[8];
      load8(base + rowoff + cchunk*8, t8);
      #pragma unroll
      for (int j = 0; j < 8; ++j) {
        int z = z0 + cchunk*8 + j;
        float zs = siluf_(t8[j]);
        qv[j] = fmaf(zs, qkg[z],     qkb[z]);
        kv[j] = fmaf(zs, qkg[128+z], qkb[128+z]);
      }
      store8bf(&qs[r*136 + z0 + cchunk*8], qv);
      store8bf(&ks[r*136 + z0 + cchunk*8], kv);
    }
  }
  __syncthreads();
  int wave = tid >> 6, lane = tid & 63;
  int fr = lane & 15, fq = lane >> 4;
  f32x4 acc[2][8];
  #pragma unroll
  for (int i = 0; i < 2; ++i)
    #pragma unroll
    for (int j = 0; j < 8; ++j)
      acc[i][j] = (f32x4){0.f,0.f,0.f,0.f};
  #pragma unroll
  for (int kk = 0; kk < 4; ++kk) {
    short8 af[2], bfr[8];
    #pragma unroll
    for (int mi = 0; mi < 2; ++mi)
      af[mi] = *(const short8*)&qs[(wave*32 + mi*16 + fr)*136 + kk*32 + fq*8];
    #pragma unroll
    for (int ni = 0; ni < 8; ++ni)
      bfr[ni] = *(const short8*)&ks[(ni*16 + fr)*136 + kk*32 + fq*8];
    #pragma unroll
    for (int mi = 0; mi < 2; ++mi)
      #pragma unroll
      for (int ni = 0; ni < 8; ++ni)
        acc[mi][ni] = __builtin_amdgcn_mfma_f32_16x16x32_bf16(
            af[mi], bfr[ni], acc[mi][ni], 0, 0, 0);
  }
  const float scale = 0.08838834764831845f;  // 1/sqrt(128)
  float mrow[2][4], srow[2][4];
  #pragma unroll
  for (int mi = 0; mi < 2; ++mi)
    #pragma unroll
    for (int r = 0; r < 4; ++r) mrow[mi][r] = -1e30f;
  #pragma unroll
  for (int mi = 0; mi < 2; ++mi)
    #pragma unroll
    for (int ni = 0; ni < 8; ++ni)
      #pragma unroll
      for (int r = 0; r < 4; ++r) {
        int i = wave*32 + mi*16 + fq*4 + r;
        int j = ni*16 + fr;
        float v = fmaf(acc[mi][ni][r], scale, rpb[1023 + j - i]);
        acc[mi][ni][r] = v;
        mrow[mi][r] = fmaxf(mrow[mi][r], v);
      }
  #pragma unroll
  for (int mi = 0; mi < 2; ++mi)
    #pragma unroll
    for (int r = 0; r < 4; ++r) {
      float m = mrow[mi][r];
      m = fmaxf(m, __shfl_xor(m, 1));
      m = fmaxf(m, __shfl_xor(m, 2));
      m = fmaxf(m, __shfl_xor(m, 4));
      m = fmaxf(m, __shfl_xor(m, 8));
      mrow[mi][r] = m;
      srow[mi][r] = 0.f;
    }
  #pragma unroll
  for (int mi = 0; mi < 2; ++mi)
    #pragma unroll
    for (int ni = 0; ni < 8; ++ni)
      #pragma unroll
      for (int r = 0; r < 4; ++r) {
        float e = __expf(acc[mi][ni][r] - mrow[mi][r]);
        acc[mi][ni][r] = e;
        srow[mi][r] += e;
      }
  #pragma unroll
  for (int mi = 0; mi < 2; ++mi)
    #pragma unroll
    for (int r = 0; r < 4; ++r) {
      float s = srow[mi][r];
      s += __shfl_xor(s, 1);
      s += __shfl_xor(s, 2);
      s += __shfl_xor(s, 4);
      s += __shfl_xor(s, 8);
      srow[mi][r] = 1.f/s;
    }
  #pragma unroll
  for (int mi = 0; mi < 2; ++mi)
    #pragma unroll
    for (int r = 0; r < 4; ++r) {
      int i = wave*32 + mi*16 + fq*4 + r;
      size_t o = ((size_t)blk*128 + i)*128;
      #pragma unroll
      for (int ni = 0; ni < 8; ++ni) {
        float val = acc[mi][ni][r]*srow[mi][r];
        attn_out[o + ni*16 + fr] = val;
        p_bf[o + ni*16 + fr] = f2bf(val);
      }
    }
}

// ---------------------------------------------------------------------------
// hr = (P @ V) * silu(r) via MFMA. P = p_bf (128x128 per blk), V = vt
// (N x K rows per (b,nchunk)). Grid flat: blk*8 + htile (A reused by 8
// consecutive blocks). Output rows (l*16+b) for the Wh GEMM.
// ---------------------------------------------------------------------------
__global__ __launch_bounds__(256) void attn_pv_kernel(
    const bf16_t* __restrict__ p_bf, const bf16_t* __restrict__ vt,
    const bf16_t* __restrict__ base, bf16_t* __restrict__ hr)
{
  __shared__ __align__(16) char smem[34816];
  bf16_t* As = (bf16_t*)smem;
  bf16_t* Bs = (bf16_t*)(smem + 8192);
  bf16_t* Cs = (bf16_t*)smem;
  int blk = blockIdx.x >> 3, ht = blockIdx.x & 7;
  int b = blk >> 4, n = blk & 15;
  const int K = 128;
  int tid = threadIdx.x;
  int wave = tid >> 6, lane = tid & 63;
  int srow = lane >> 2, schunk = lane & 3;
  const bf16_t* A = p_bf + (size_t)blk*(128*128);
  const bf16_t* Bt = vt + ((size_t)blk*H_DIM + ht*128)*128;
  const bf16_t* Ag0 = A + (size_t)(wave*16 + srow)*K + schunk*8;
  const bf16_t* Ag1 = Ag0 + (size_t)64*K;
  const bf16_t* Bg0 = Bt + (size_t)(wave*16 + srow)*K + schunk*8;
  const bf16_t* Bg1 = Bg0 + (size_t)64*K;
  bf16_t* Asl0 = As + (wave*16)*32;
  bf16_t* Asl1 = As + (64 + wave*16)*32;
  bf16_t* Bsl0 = Bs + (wave*16)*32;
  bf16_t* Bsl1 = Bs + (64 + wave*16)*32;

  int wm = wave >> 1, wn = wave & 1;
  int fr = lane & 15, fq = lane >> 4;
  f32x4 acc[4][4];
  #pragma unroll
  for (int i = 0; i < 4; ++i)
    #pragma unroll
    for (int j = 0; j < 4; ++j)
      acc[i][j] = (f32x4){0.f,0.f,0.f,0.f};

  for (int k0 = 0; k0 < K; k0 += 32) {
    __syncthreads();
    glds16(Ag0 + k0, Asl0);
    glds16(Ag1 + k0, Asl1);
    glds16(Bg0 + k0, Bsl0);
    glds16(Bg1 + k0, Bsl1);
    __syncthreads();
    short8 af[4], bfr[4];
    #pragma unroll
    for (int mi = 0; mi < 4; ++mi)
      af[mi] = *(const short8*)&As[(wm*64 + mi*16 + fr)*32 + fq*8];
    #pragma unroll
    for (int ni = 0; ni < 4; ++ni)
      bfr[ni] = *(const short8*)&Bs[(wn*64 + ni*16 + fr)*32 + fq*8];
    #pragma unroll
    for (int mi = 0; mi < 4; ++mi)
      #pragma unroll
      for (int ni = 0; ni < 4; ++ni)
        acc[mi][ni] = __builtin_amdgcn_mfma_f32_16x16x32_bf16(
            af[mi], bfr[ni], acc[mi][ni], 0, 0, 0);
  }

  __syncthreads();
  #pragma unroll
  for (int ni = 0; ni < 4; ++ni) {
    int cl = wn*64 + ni*16 + fr;
    int hg = ht*128 + cl;
    #pragma unroll
    for (int mi = 0; mi < 4; ++mi) {
      #pragma unroll
      for (int r = 0; r < 4; ++r) {
        int ml = wm*64 + mi*16 + fq*4 + r;
        size_t rowg = (size_t)((n*128 + ml)*B_DIM + b);
        float rg = bf2f(base[rowg*BASE_N + 640 + hg]);
        Cs[ml*136 + cl] = f2bf(acc[mi][ni][r]*siluf_(rg));
      }
    }
  }
  __syncthreads();
  int row = tid >> 1, c0 = (tid & 1)*64;
  size_t rowg = (size_t)((n*128 + row)*B_DIM + b);
  #pragma unroll
  for (int q = 0; q < 8; ++q)
    *(uint4*)(hr + rowg*H_DIM + ht*128 + c0 + q*8) =
        *(const uint4*)&Cs[row*136 + c0 + q*8];
}

// ---------------------------------------------------------------------------
// out = residual + u*(h2 - residual), then RMSNorm * norm_scalar.
// ---------------------------------------------------------------------------
__global__ __launch_bounds__(64) void final_kernel(
    const float* __restrict__ x, const bf16_t* __restrict__ h2,
    const bf16_t* __restrict__ base, const float* __restrict__ ns,
    float* __restrict__ out)
{
  int row = blockIdx.x;
  int t = threadIdx.x;
  size_t ro = (size_t)row*D_DIM + t*8;
  float xv[8]; load8(x + ro, xv);
  float hv[8]; load8(h2 + ro, hv);
  float uv[8]; load8(base + (size_t)row*BASE_N + t*8, uv);
  float o[8];
  float ss = 0.f;
  #pragma unroll
  for (int i = 0; i < 8; ++i) {
    float u = sigmoidf_(uv[i]);
    o[i] = xv[i] + u*(hv[i] - xv[i]);
    ss += o[i]*o[i];
  }
  #pragma unroll
  for (int m = 1; m < 64; m <<= 1) ss += __shfl_xor(ss, m);
  float inv = rsqrtf(ss*(1.f/(float)D_DIM) + 1e-6f) * ns[0];
  float4 r0, r1;
  r0.x = o[0]*inv; r0.y = o[1]*inv; r0.z = o[2]*inv; r0.w = o[3]*inv;
  r1.x = o[4]*inv; r1.y = o[5]*inv; r1.z = o[6]*inv; r1.w = o[7]*inv;
  *(float4*)(out + ro) = r0;
  *(float4*)(out + ro + 4) = r1;
}

// ---------------------------------------------------------------------------
extern "C" void kernel_launch(void* const* d_in, const int* in_sizes, int n_in,
                              void* d_out, int out_size, void* d_ws, size_t ws_size,
                              hipStream_t stream)
{
  const float* x     = (const float*)d_in[0];
  const float* delta = (const float*)d_in[1];
  const float* alpha = (const float*)d_in[2];
  const float* beta  = (const float*)d_in[3];
  const float* gamma = (const float*)d_in[4];
  const float* omega = (const float*)d_in[5];
  const float* Wv    = (const float*)d_in[6];
  const float* bv    = (const float*)d_in[7];
  const float* Wmx   = (const float*)d_in[8];
  const float* bmx   = (const float*)d_in[9];
  const float* Wh    = (const float*)d_in[10];
  const float* bh    = (const float*)d_in[11];
  const float* qkg   = (const float*)d_in[12];
  const float* qkb   = (const float*)d_in[13];
  const float* rpb   = (const float*)d_in[14];
  const float* ns    = (const float*)d_in[15];

  float* out  = (float*)d_out;
  float* attn = out + (size_t)ROWS*D_DIM;          // bytes [67,108,864, 83,886,080)

  // d_out scratch (dead before final_kernel writes out over it):
  //   x_bf  [0, 33.5M)  — live until Wv GEMM + ema_apply
  //   p_bf  [0,  8.4M)  — written by scores (after x_bf dead), read by PV
  //   Wv_t  [33,554,432, ...), Wmx_t, Wh_t
  char* outb = (char*)d_out;
  bf16_t* x_bf  = (bf16_t*)outb;
  bf16_t* p_bf  = (bf16_t*)outb;
  bf16_t* Wv_t  = (bf16_t*)(outb + 33554432ull);
  bf16_t* Wmx_t = (bf16_t*)(outb + 34603008ull);
  bf16_t* Wh_t  = (bf16_t*)(outb + 36831232ull);

  // Workspace (>= 310,378,496 B, verified round 2):
  //  [0,            33,554,432)  mx bf16  -> later h2 bf16
  //  [33,554,432,  100,663,296)  vt bf16 [b][nchunk][h][k]
  //  [100,663,296, 243,269,632)  base bf16; first 4 MB = carry during EMA
  //  [243,269,632, 310,378,496)  hr bf16
  const size_t WS_NEED = 310378496ull;
  if (ws_size < WS_NEED) return;
  char* wsb = (char*)d_ws;
  bf16_t* mx_bf   = (bf16_t*)(wsb);
  bf16_t* vt      = (bf16_t*)(wsb + 33554432ull);
  bf16_t* base_bf = (bf16_t*)(wsb + 100663296ull);
  bf16_t* hr_bf   = (bf16_t*)(wsb + 243269632ull);
  float*  carry   = (float*)(wsb + 100663296ull);
  bf16_t* h2_bf   = mx_bf;

  // weight transposes
  transpose_cvt_kernel<<<dim3(32, 16), 256, 0, stream>>>(Wv,  Wv_t,  512, 1024);
  transpose_cvt_kernel<<<dim3(68, 16), 256, 0, stream>>>(Wmx, Wmx_t, 512, 2176);
  transpose_cvt_kernel<<<dim3(16, 32), 256, 0, stream>>>(Wh,  Wh_t,  1024, 512);
  // EMA segmented scan (also produces x_bf)
  ema_carry_kernel<<<1024, 256, 0, stream>>>(x, delta, alpha, x_bf, carry);
  ema_combine_kernel<<<32, 256, 0, stream>>>(delta, alpha, carry);
  ema_apply_kernel<<<1024, 256, 0, stream>>>(x_bf, delta, alpha, beta, gamma,
                                             omega, carry, mx_bf);
  // vt = silu(x @ Wv + bv), transposed per 128-chunk
  mfma_gemm_v_kernel<<<2048, 256, 0, stream>>>(x_bf, Wv_t, bv, vt, 8, D_DIM);
  // base = mx @ Wmx + bmx
  mfma_gemm_kernel<<<4352, 256, 0, stream>>>(
      mx_bf, Wmx_t, bmx, nullptr, 0, base_bf, BASE_N, D_DIM, 17, 0);
  // attn probs (fp32 -> d_out, bf16 -> p_bf)
  attn_scores_mfma_kernel<<<B_DIM*NC, 256, 0, stream>>>(
      base_bf, qkg, qkb, rpb, attn, p_bf);
  // hr = (P @ V) * silu(r)
  attn_pv_kernel<<<2048, 256, 0, stream>>>(p_bf, vt, base_bf, hr_bf);
  // h2 = silu(hx + hr @ Wh + bh)
  mfma_gemm_kernel<<<1024, 256, 0, stream>>>(
      hr_bf, Wh_t, bh, base_bf + 1664, BASE_N, h2_bf, D_DIM, H_DIM, 4, 1);
  // gated residual + RMSNorm
  final_kernel<<<ROWS, 64, 0, stream>>>(x, h2_bf, base_bf, ns, out);
}

// Round 5
// 649.962 us; speedup vs baseline: 4.0892x; 1.0440x over previous
//
#include <hip/hip_runtime.h>
#include <math.h>

// Problem dims
#define L_DIM 2048
#define B_DIM 16
#define D_DIM 512
#define H_DIM 1024
#define Z_DIM 128
#define NC    16
#define BASE_N 2176            // Z + H + 2D
#define ROWS  (L_DIM*B_DIM)    // 32768
#define NSEG  32
#define SLEN  64
#define CHAINS 8192            // B*D

typedef unsigned short bf16_t;
typedef __attribute__((ext_vector_type(8))) short short8;
typedef __attribute__((ext_vector_type(4))) float f32x4;

__device__ __forceinline__ float sigmoidf_(float x){ return 1.f/(1.f+__expf(-x)); }
__device__ __forceinline__ float siluf_(float x){ return x/(1.f+__expf(-x)); }
__device__ __forceinline__ float fbits(unsigned int b){ union{unsigned int i; float f;} c; c.i=b; return c.f; }
__device__ __forceinline__ unsigned short f2bf(float f){
  union{float f; unsigned int i;} c; c.f=f;
  unsigned int r = c.i + 0x7FFFu + ((c.i>>16)&1u);   // RNE
  return (unsigned short)(r>>16);
}
__device__ __forceinline__ float bf2f(unsigned short u){ return fbits(((unsigned int)u)<<16); }

__device__ __forceinline__ void load8(const float* __restrict__ p, float* d){
  float4 a = *(const float4*)p; float4 b = *(const float4*)(p+4);
  d[0]=a.x; d[1]=a.y; d[2]=a.z; d[3]=a.w; d[4]=b.x; d[5]=b.y; d[6]=b.z; d[7]=b.w;
}
__device__ __forceinline__ void load8(const bf16_t* __restrict__ p, float* d){
  uint4 u = *(const uint4*)p;
  d[0]=fbits(u.x<<16); d[1]=fbits(u.x&0xFFFF0000u);
  d[2]=fbits(u.y<<16); d[3]=fbits(u.y&0xFFFF0000u);
  d[4]=fbits(u.z<<16); d[5]=fbits(u.z&0xFFFF0000u);
  d[6]=fbits(u.w<<16); d[7]=fbits(u.w&0xFFFF0000u);
}
__device__ __forceinline__ void store8bf(bf16_t* p, const float* v){
  uint4 s;
  s.x = (unsigned int)f2bf(v[0]) | ((unsigned int)f2bf(v[1])<<16);
  s.y = (unsigned int)f2bf(v[2]) | ((unsigned int)f2bf(v[3])<<16);
  s.z = (unsigned int)f2bf(v[4]) | ((unsigned int)f2bf(v[5])<<16);
  s.w = (unsigned int)f2bf(v[6]) | ((unsigned int)f2bf(v[7])<<16);
  *(uint4*)p = s;
}

// async global(16B/lane) -> LDS, wave-uniform LDS base + lane*16
__device__ __forceinline__ void glds16(const void* g, void* l) {
  __builtin_amdgcn_global_load_lds(
      (const __attribute__((address_space(1))) unsigned int*)g,
      (__attribute__((address_space(3))) unsigned int*)l, 16, 0, 0);
}

// ---------------------------------------------------------------------------
// All three weight transposes in one launch. W (K x N fp32) -> Wt (N x K bf16)
// ---------------------------------------------------------------------------
__global__ __launch_bounds__(256) void transpose_all_kernel(
    const float* __restrict__ Wv, const float* __restrict__ Wmx,
    const float* __restrict__ Wh, bf16_t* __restrict__ Wvt,
    bf16_t* __restrict__ Wmxt, bf16_t* __restrict__ Wht)
{
  __shared__ float t[32][33];
  int blk = blockIdx.x;
  const float* W; bf16_t* Wt; int K, N, bx, by;
  if (blk < 512)       { W=Wv;  Wt=Wvt;  K=512;  N=1024; bx=blk&31;  by=blk>>5; }
  else if (blk < 1600) { blk-=512;  W=Wmx; Wt=Wmxt; K=512;  N=2176; bx=blk%68; by=blk/68; }
  else                 { blk-=1600; W=Wh;  Wt=Wht;  K=1024; N=512;  bx=blk&15; by=blk>>4; }
  int lx = threadIdx.x & 31, ly = threadIdx.x >> 5;
  #pragma unroll
  for (int i = 0; i < 32; i += 8)
    t[ly+i][lx] = W[(size_t)(by*32+ly+i)*N + bx*32 + lx];
  __syncthreads();
  #pragma unroll
  for (int i = 0; i < 32; i += 8)
    Wt[(size_t)(bx*32+ly+i)*K + by*32 + lx] = f2bf(t[lx][ly+i]);
}

// ---------------------------------------------------------------------------
// EMA segmented scan, SLEN=64, NSEG=32. Chains c = b*512+d (8192).
// ---------------------------------------------------------------------------
__global__ __launch_bounds__(256) void ema_carry_kernel(
    const float* __restrict__ x, const float* __restrict__ delta,
    const float* __restrict__ alpha, bf16_t* __restrict__ xb,
    float* __restrict__ carry)
{
  int idx = blockIdx.x*256 + threadIdx.x;      // 0..262143
  int d = idx & 511, c = idx & 8191, s = idx >> 13;   // s in 0..31
  float qf0 = 1.f - sigmoidf_(delta[d*2+0])*sigmoidf_(alpha[d*2+0]);
  float qf1 = 1.f - sigmoidf_(delta[d*2+1])*sigmoidf_(alpha[d*2+1]);
  int dd = d + 512;
  float qb0 = 1.f - sigmoidf_(delta[dd*2+0])*sigmoidf_(alpha[dd*2+0]);
  float qb1 = 1.f - sigmoidf_(delta[dd*2+1])*sigmoidf_(alpha[dd*2+1]);
  size_t off = (size_t)s*SLEN*CHAINS + c;
  float h0=0.f, h1=0.f;
  #pragma unroll
  for (int t = 0; t < SLEN; ++t) {
    size_t a = off + (size_t)t*CHAINS;
    float xv = x[a];
    xb[a] = f2bf(xv);
    h0 = fmaf(qf0, h0, xv); h1 = fmaf(qf1, h1, xv);
  }
  float g0=0.f, g1=0.f;
  #pragma unroll
  for (int t = SLEN-1; t >= 0; --t) {
    float xv = bf2f(xb[off + (size_t)t*CHAINS]);   // L2-hot reread
    g0 = fmaf(qb0, g0, xv); g1 = fmaf(qb1, g1, xv);
  }
  carry[(size_t)s*CHAINS + c]              = h0;
  carry[(size_t)s*CHAINS + c + 262144]     = h1;
  carry[(size_t)s*CHAINS + c + 524288]     = g0;
  carry[(size_t)s*CHAINS + c + 786432]     = g1;
}

__global__ __launch_bounds__(256) void ema_combine_kernel(
    const float* __restrict__ delta, const float* __restrict__ alpha,
    float* __restrict__ carry)
{
  int c = blockIdx.x*256 + threadIdx.x;   // 0..8191
  int d = c & 511;
  float qf0 = 1.f - sigmoidf_(delta[d*2+0])*sigmoidf_(alpha[d*2+0]);
  float qf1 = 1.f - sigmoidf_(delta[d*2+1])*sigmoidf_(alpha[d*2+1]);
  int dd = d + 512;
  float qb0 = 1.f - sigmoidf_(delta[dd*2+0])*sigmoidf_(alpha[dd*2+0]);
  float qb1 = 1.f - sigmoidf_(delta[dd*2+1])*sigmoidf_(alpha[dd*2+1]);
  float df0=qf0, df1=qf1, db0=qb0, db1=qb1;
  #pragma unroll
  for (int i = 0; i < 6; ++i) { df0*=df0; df1*=df1; db0*=db0; db1*=db1; }  // q^64
  float h0=0.f, h1=0.f;
  for (int s = 0; s < NSEG; ++s) {
    size_t a = (size_t)s*CHAINS + c;
    float t0 = carry[a], t1 = carry[a+262144];
    carry[a] = h0; carry[a+262144] = h1;
    h0 = fmaf(df0, h0, t0); h1 = fmaf(df1, h1, t1);
  }
  float g0=0.f, g1=0.f;
  for (int s = NSEG-1; s >= 0; --s) {
    size_t a = (size_t)s*CHAINS + c;
    float t0 = carry[a+524288], t1 = carry[a+786432];
    carry[a+524288] = g0; carry[a+786432] = g1;
    g0 = fmaf(db0, g0, t0); g1 = fmaf(db1, g1, t1);
  }
}

__global__ __launch_bounds__(256) void ema_apply_kernel(
    const bf16_t* __restrict__ xb, const float* __restrict__ delta,
    const float* __restrict__ alpha, const float* __restrict__ beta,
    const float* __restrict__ gamma, const float* __restrict__ omega,
    const float* __restrict__ carry, bf16_t* __restrict__ mx)
{
  int idx = blockIdx.x*256 + threadIdx.x;
  int d = idx & 511, c = idx & 8191, s = idx >> 13;
  const float rs = 0.70710678118654752f;
  float pf0 = sigmoidf_(delta[d*2+0]), pf1 = sigmoidf_(delta[d*2+1]);
  float qf0 = 1.f - pf0*sigmoidf_(alpha[d*2+0]);
  float qf1 = 1.f - pf1*sigmoidf_(alpha[d*2+1]);
  float cf0 = pf0*beta[d*2+0]*gamma[d*2+0]*rs;
  float cf1 = pf1*beta[d*2+1]*gamma[d*2+1]*rs;
  int dd = d + 512;
  float pb0 = sigmoidf_(delta[dd*2+0]), pb1 = sigmoidf_(delta[dd*2+1]);
  float qb0 = 1.f - pb0*sigmoidf_(alpha[dd*2+0]);
  float qb1 = 1.f - pb1*sigmoidf_(alpha[dd*2+1]);
  float cb0 = pb0*beta[dd*2+0]*gamma[dd*2+0]*rs;
  float cb1 = pb1*beta[dd*2+1]*gamma[dd*2+1]*rs;
  float om = omega[d];
  size_t off = (size_t)s*SLEN*CHAINS + c;
  float h0 = carry[(size_t)s*CHAINS + c];
  float h1 = carry[(size_t)s*CHAINS + c + 262144];
  float yv[SLEN];
  #pragma unroll
  for (int t = 0; t < SLEN; ++t) {
    float xv = bf2f(xb[off + (size_t)t*CHAINS]);
    h0 = fmaf(qf0, h0, xv); h1 = fmaf(qf1, h1, xv);
    yv[t] = fmaf(cf0, h0, cf1*h1);
  }
  float g0 = carry[(size_t)s*CHAINS + c + 524288];
  float g1 = carry[(size_t)s*CHAINS + c + 786432];
  #pragma unroll
  for (int t = SLEN-1; t >= 0; --t) {
    size_t a = off + (size_t)t*CHAINS;
    float xv = bf2f(xb[a]);
    g0 = fmaf(qb0, g0, xv); g1 = fmaf(qb1, g1, xv);
    float sv = yv[t] + fmaf(cb0, g0, cb1*g1) + xv*om;
    mx[a] = f2bf(siluf_(sv));
  }
}

// ===========================================================================
// Shared MFMA K-loop core, BK=64, XOR-swizzled LDS (slot = (chunk+row)&7):
// consecutive lanes hit distinct 16B bank groups on both staging and reads.
// As/Bs rows are 64 bf16 = 128 B. Staging: lane loads global chunk
// c = ((lane&7)-(lane>>3))&7 so it lands at slot (c+row)&7.
// ===========================================================================
#define GEMM_PROLOG(Aptr, Bptr, Kdim)                                        \
  int tid = threadIdx.x;                                                     \
  int wave = tid >> 6, lane = tid & 63;                                      \
  int lrow = lane >> 3, lchunk = ((lane & 7) - lrow) & 7;                    \
  const bf16_t* Ag = (Aptr) + (size_t)(wave*32 + lrow)*(Kdim) + lchunk*8;    \
  const bf16_t* Bg = (Bptr) + (size_t)(wave*32 + lrow)*(Kdim) + lchunk*8;    \
  int wm = wave >> 1, wn = wave & 1;                                         \
  int fr = lane & 15, fq = lane >> 4;                                        \
  f32x4 acc[4][4];                                                           \
  _Pragma("unroll") for (int i = 0; i < 4; ++i)                              \
    _Pragma("unroll") for (int j = 0; j < 4; ++j)                            \
      acc[i][j] = (f32x4){0.f,0.f,0.f,0.f};

#define GEMM_KLOOP(Kdim)                                                     \
  for (int k0 = 0; k0 < (Kdim); k0 += 64) {                                  \
    __syncthreads();                                                         \
    _Pragma("unroll") for (int j = 0; j < 4; ++j) {                          \
      glds16(Ag + (size_t)j*8*(Kdim) + k0, As + (wave*32 + j*8)*64);         \
      glds16(Bg + (size_t)j*8*(Kdim) + k0, Bs + (wave*32 + j*8)*64);         \
    }                                                                        \
    __syncthreads();                                                         \
    _Pragma("unroll") for (int kk = 0; kk < 2; ++kk) {                       \
      short8 af[4], bfr[4];                                                  \
      _Pragma("unroll") for (int mi = 0; mi < 4; ++mi) {                     \
        int R = wm*64 + mi*16 + fr;                                          \
        af[mi] = *(const short8*)&As[R*64 + (((kk<<2)+fq+R)&7)*8];           \
      }                                                                      \
      _Pragma("unroll") for (int ni = 0; ni < 4; ++ni) {                     \
        int R = wn*64 + ni*16 + fr;                                          \
        bfr[ni] = *(const short8*)&Bs[R*64 + (((kk<<2)+fq+R)&7)*8];          \
      }                                                                      \
      _Pragma("unroll") for (int mi = 0; mi < 4; ++mi)                       \
        _Pragma("unroll") for (int ni = 0; ni < 4; ++ni)                     \
          acc[mi][ni] = __builtin_amdgcn_mfma_f32_16x16x32_bf16(             \
              af[mi], bfr[ni], acc[mi][ni], 0, 0, 0);                        \
    }                                                                        \
  }

// ---------------------------------------------------------------------------
// Generic MFMA bf16 GEMM: C(bf16, MxN) = act(A @ Bt^T + bias [+ Add])
// 128x128 tile, XCD-swizzled 1-D grid. Epilogue repacks via LDS, dwordx4.
// ---------------------------------------------------------------------------
__global__ __launch_bounds__(256) void mfma_gemm_kernel(
    const bf16_t* __restrict__ A, const bf16_t* __restrict__ Bt,
    const float* __restrict__ bias, const bf16_t* __restrict__ Add, int addLd,
    bf16_t* __restrict__ C, int N, int K, int nT, int act)
{
  __shared__ __align__(16) char smem[34816];
  bf16_t* As = (bf16_t*)smem;            // 128x64
  bf16_t* Bs = (bf16_t*)(smem + 16384);  // 128x64
  bf16_t* Cs = (bf16_t*)smem;            // 128x136 (reuse after K-loop)
  int flat = blockIdx.x;
  int xcd = flat & 7, g = flat >> 3;
  int mT8 = (int)(gridDim.x / (unsigned)nT) >> 3;
  int mt = xcd*mT8 + g / nT;
  int nt = g % nT;
  int m0 = mt*128, n0 = nt*128;
  GEMM_PROLOG(A + (size_t)m0*K, Bt + (size_t)n0*K, K)
  GEMM_KLOOP(K)
  __syncthreads();
  #pragma unroll
  for (int ni = 0; ni < 4; ++ni) {
    int cl = wn*64 + ni*16 + fr;
    int gn = n0 + cl;
    float bv = bias[gn];
    #pragma unroll
    for (int mi = 0; mi < 4; ++mi) {
      #pragma unroll
      for (int r = 0; r < 4; ++r) {
        int ml = wm*64 + mi*16 + fq*4 + r;
        float val = acc[mi][ni][r] + bv;
        if (Add) val += bf2f(Add[(size_t)(m0+ml)*addLd + gn]);
        if (act == 1) val = siluf_(val);
        Cs[ml*136 + cl] = f2bf(val);
      }
    }
  }
  __syncthreads();
  int row = tid >> 1, c0 = (tid & 1)*64;
  #pragma unroll
  for (int q = 0; q < 8; ++q)
    *(uint4*)(C + (size_t)(m0+row)*N + n0 + c0 + q*8) =
        *(const uint4*)&Cs[row*136 + c0 + q*8];
}

// ---------------------------------------------------------------------------
// Wv GEMM variant: vt[b][nchunk][h][k] = silu(x @ Wv + bv), transposed per
// 128-chunk so PV can consume it as an N x K "Bt". N = 1024, K = 512.
// ---------------------------------------------------------------------------
__global__ __launch_bounds__(256) void mfma_gemm_v_kernel(
    const bf16_t* __restrict__ A, const bf16_t* __restrict__ Bt,
    const float* __restrict__ bias, bf16_t* __restrict__ vt, int nT, int K)
{
  __shared__ __align__(16) char smem[34816];
  bf16_t* As = (bf16_t*)smem;
  bf16_t* Bs = (bf16_t*)(smem + 16384);
  bf16_t* Cs = (bf16_t*)smem;
  int flat = blockIdx.x;
  int xcd = flat & 7, g = flat >> 3;
  int mT8 = (int)(gridDim.x / (unsigned)nT) >> 3;
  int mt = xcd*mT8 + g / nT;
  int nt = g % nT;
  int m0 = mt*128, n0 = nt*128;
  GEMM_PROLOG(A + (size_t)m0*K, Bt + (size_t)n0*K, K)
  GEMM_KLOOP(K)
  __syncthreads();
  #pragma unroll
  for (int ni = 0; ni < 4; ++ni) {
    int cl = wn*64 + ni*16 + fr;
    float bv = bias[n0 + cl];
    #pragma unroll
    for (int mi = 0; mi < 4; ++mi) {
      #pragma unroll
      for (int r = 0; r < 4; ++r) {
        int ml = wm*64 + mi*16 + fq*4 + r;
        Cs[ml*136 + cl] = f2bf(siluf_(acc[mi][ni][r] + bv));
      }
    }
  }
  __syncthreads();
  // Tile rows gm = m0 + (kk*16 + b): vt[(b*16+nchunk)*1024 + h][k],
  // nchunk = mt>>4, k = (mt&15)*8 + kk.
  int b = tid >> 4, h0l = (tid & 15)*8;
  int nchunk = mt >> 4, kbase = (mt & 15)*8;
  #pragma unroll
  for (int j = 0; j < 8; ++j) {
    int hl = h0l + j;
    uint4 s;
    s.x = (unsigned int)Cs[(0*16 + b)*136 + hl] |
          ((unsigned int)Cs[(1*16 + b)*136 + hl] << 16);
    s.y = (unsigned int)Cs[(2*16 + b)*136 + hl] |
          ((unsigned int)Cs[(3*16 + b)*136 + hl] << 16);
    s.z = (unsigned int)Cs[(4*16 + b)*136 + hl] |
          ((unsigned int)Cs[(5*16 + b)*136 + hl] << 16);
    s.w = (unsigned int)Cs[(6*16 + b)*136 + hl] |
          ((unsigned int)Cs[(7*16 + b)*136 + hl] << 16);
    *(uint4*)&vt[((size_t)(b*NC + nchunk)*H_DIM + n0 + hl)*128 + kbase] = s;
  }
}

// ---------------------------------------------------------------------------
// Attention scores via MFMA + softmax. One block per (b,n).
// Writes fp32 probs to d_out AND bf16 probs (p_bf) for the PV GEMM.
// ---------------------------------------------------------------------------
__global__ __launch_bounds__(256) void attn_scores_mfma_kernel(
    const bf16_t* __restrict__ base, const float* __restrict__ qkg,
    const float* __restrict__ qkb, const float* __restrict__ rpb,
    float* __restrict__ attn_out, bf16_t* __restrict__ p_bf)
{
  __shared__ bf16_t qs[128*136];
  __shared__ bf16_t ks[128*136];
  int blk = blockIdx.x;            // b*16 + n
  int b = blk >> 4, n = blk & 15;
  int tid = threadIdx.x;
  {
    int r = tid >> 1, z0 = (tid & 1)*64;
    size_t rowoff = ((size_t)((n*128 + r)*B_DIM + b))*BASE_N + 512 + z0;
    #pragma unroll
    for (int cchunk = 0; cchunk < 8; ++cchunk) {
      float t8[8], qv[8], kv[8];
      load8(base + rowoff + cchunk*8, t8);
      #pragma unroll
      for (int j = 0; j < 8; ++j) {
        int z = z0 + cchunk*8 + j;
        float zs = siluf_(t8[j]);
        qv[j] = fmaf(zs, qkg[z],     qkb[z]);
        kv[j] = fmaf(zs, qkg[128+z], qkb[128+z]);
      }
      store8bf(&qs[r*136 + z0 + cchunk*8], qv);
      store8bf(&ks[r*136 + z0 + cchunk*8], kv);
    }
  }
  __syncthreads();
  int wave = tid >> 6, lane = tid & 63;
  int fr = lane & 15, fq = lane >> 4;
  f32x4 acc[2][8];
  #pragma unroll
  for (int i = 0; i < 2; ++i)
    #pragma unroll
    for (int j = 0; j < 8; ++j)
      acc[i][j] = (f32x4){0.f,0.f,0.f,0.f};
  #pragma unroll
  for (int kk = 0; kk < 4; ++kk) {
    short8 af[2], bfr[8];
    #pragma unroll
    for (int mi = 0; mi < 2; ++mi)
      af[mi] = *(const short8*)&qs[(wave*32 + mi*16 + fr)*136 + kk*32 + fq*8];
    #pragma unroll
    for (int ni = 0; ni < 8; ++ni)
      bfr[ni] = *(const short8*)&ks[(ni*16 + fr)*136 + kk*32 + fq*8];
    #pragma unroll
    for (int mi = 0; mi < 2; ++mi)
      #pragma unroll
      for (int ni = 0; ni < 8; ++ni)
        acc[mi][ni] = __builtin_amdgcn_mfma_f32_16x16x32_bf16(
            af[mi], bfr[ni], acc[mi][ni], 0, 0, 0);
  }
  const float scale = 0.08838834764831845f;  // 1/sqrt(128)
  float mrow[2][4], srow[2][4];
  #pragma unroll
  for (int mi = 0; mi < 2; ++mi)
    #pragma unroll
    for (int r = 0; r < 4; ++r) mrow[mi][r] = -1e30f;
  #pragma unroll
  for (int mi = 0; mi < 2; ++mi)
    #pragma unroll
    for (int ni = 0; ni < 8; ++ni)
      #pragma unroll
      for (int r = 0; r < 4; ++r) {
        int i = wave*32 + mi*16 + fq*4 + r;
        int j = ni*16 + fr;
        float v = fmaf(acc[mi][ni][r], scale, rpb[1023 + j - i]);
        acc[mi][ni][r] = v;
        mrow[mi][r] = fmaxf(mrow[mi][r], v);
      }
  #pragma unroll
  for (int mi = 0; mi < 2; ++mi)
    #pragma unroll
    for (int r = 0; r < 4; ++r) {
      float m = mrow[mi][r];
      m = fmaxf(m, __shfl_xor(m, 1));
      m = fmaxf(m, __shfl_xor(m, 2));
      m = fmaxf(m, __shfl_xor(m, 4));
      m = fmaxf(m, __shfl_xor(m, 8));
      mrow[mi][r] = m;
      srow[mi][r] = 0.f;
    }
  #pragma unroll
  for (int mi = 0; mi < 2; ++mi)
    #pragma unroll
    for (int ni = 0; ni < 8; ++ni)
      #pragma unroll
      for (int r = 0; r < 4; ++r) {
        float e = __expf(acc[mi][ni][r] - mrow[mi][r]);
        acc[mi][ni][r] = e;
        srow[mi][r] += e;
      }
  #pragma unroll
  for (int mi = 0; mi < 2; ++mi)
    #pragma unroll
    for (int r = 0; r < 4; ++r) {
      float s = srow[mi][r];
      s += __shfl_xor(s, 1);
      s += __shfl_xor(s, 2);
      s += __shfl_xor(s, 4);
      s += __shfl_xor(s, 8);
      srow[mi][r] = 1.f/s;
    }
  #pragma unroll
  for (int mi = 0; mi < 2; ++mi)
    #pragma unroll
    for (int r = 0; r < 4; ++r) {
      int i = wave*32 + mi*16 + fq*4 + r;
      size_t o = ((size_t)blk*128 + i)*128;
      #pragma unroll
      for (int ni = 0; ni < 8; ++ni) {
        float val = acc[mi][ni][r]*srow[mi][r];
        attn_out[o + ni*16 + fr] = val;
        p_bf[o + ni*16 + fr] = f2bf(val);
      }
    }
}

// ---------------------------------------------------------------------------
// hr = (P @ V) * silu(r) via MFMA. Grid flat: blk*8 + htile.
// ---------------------------------------------------------------------------
__global__ __launch_bounds__(256) void attn_pv_kernel(
    const bf16_t* __restrict__ p_bf, const bf16_t* __restrict__ vt,
    const bf16_t* __restrict__ base, bf16_t* __restrict__ hr)
{
  __shared__ __align__(16) char smem[34816];
  bf16_t* As = (bf16_t*)smem;
  bf16_t* Bs = (bf16_t*)(smem + 16384);
  bf16_t* Cs = (bf16_t*)smem;
  int blk = blockIdx.x >> 3, ht = blockIdx.x & 7;
  int b = blk >> 4, n = blk & 15;
  const int K = 128;
  GEMM_PROLOG(p_bf + (size_t)blk*(128*128),
              vt + ((size_t)blk*H_DIM + ht*128)*128, K)
  GEMM_KLOOP(K)
  __syncthreads();
  #pragma unroll
  for (int ni = 0; ni < 4; ++ni) {
    int cl = wn*64 + ni*16 + fr;
    int hg = ht*128 + cl;
    #pragma unroll
    for (int mi = 0; mi < 4; ++mi) {
      #pragma unroll
      for (int r = 0; r < 4; ++r) {
        int ml = wm*64 + mi*16 + fq*4 + r;
        size_t rowg = (size_t)((n*128 + ml)*B_DIM + b);
        float rg = bf2f(base[rowg*BASE_N + 640 + hg]);
        Cs[ml*136 + cl] = f2bf(acc[mi][ni][r]*siluf_(rg));
      }
    }
  }
  __syncthreads();
  int row = tid >> 1, c0 = (tid & 1)*64;
  size_t rowg = (size_t)((n*128 + row)*B_DIM + b);
  #pragma unroll
  for (int q = 0; q < 8; ++q)
    *(uint4*)(hr + rowg*H_DIM + ht*128 + c0 + q*8) =
        *(const uint4*)&Cs[row*136 + c0 + q*8];
}

// ---------------------------------------------------------------------------
// out = residual + u*(h2 - residual), then RMSNorm * norm_scalar.
// ---------------------------------------------------------------------------
__global__ __launch_bounds__(64) void final_kernel(
    const float* __restrict__ x, const bf16_t* __restrict__ h2,
    const bf16_t* __restrict__ base, const float* __restrict__ ns,
    float* __restrict__ out)
{
  int row = blockIdx.x;
  int t = threadIdx.x;
  size_t ro = (size_t)row*D_DIM + t*8;
  float xv[8]; load8(x + ro, xv);
  float hv[8]; load8(h2 + ro, hv);
  float uv[8]; load8(base + (size_t)row*BASE_N + t*8, uv);
  float o[8];
  float ss = 0.f;
  #pragma unroll
  for (int i = 0; i < 8; ++i) {
    float u = sigmoidf_(uv[i]);
    o[i] = xv[i] + u*(hv[i] - xv[i]);
    ss += o[i]*o[i];
  }
  #pragma unroll
  for (int m = 1; m < 64; m <<= 1) ss += __shfl_xor(ss, m);
  float inv = rsqrtf(ss*(1.f/(float)D_DIM) + 1e-6f) * ns[0];
  float4 r0, r1;
  r0.x = o[0]*inv; r0.y = o[1]*inv; r0.z = o[2]*inv; r0.w = o[3]*inv;
  r1.x = o[4]*inv; r1.y = o[5]*inv; r1.z = o[6]*inv; r1.w = o[7]*inv;
  *(float4*)(out + ro) = r0;
  *(float4*)(out + ro + 4) = r1;
}

// ---------------------------------------------------------------------------
extern "C" void kernel_launch(void* const* d_in, const int* in_sizes, int n_in,
                              void* d_out, int out_size, void* d_ws, size_t ws_size,
                              hipStream_t stream)
{
  const float* x     = (const float*)d_in[0];
  const float* delta = (const float*)d_in[1];
  const float* alpha = (const float*)d_in[2];
  const float* beta  = (const float*)d_in[3];
  const float* gamma = (const float*)d_in[4];
  const float* omega = (const float*)d_in[5];
  const float* Wv    = (const float*)d_in[6];
  const float* bv    = (const float*)d_in[7];
  const float* Wmx   = (const float*)d_in[8];
  const float* bmx   = (const float*)d_in[9];
  const float* Wh    = (const float*)d_in[10];
  const float* bh    = (const float*)d_in[11];
  const float* qkg   = (const float*)d_in[12];
  const float* qkb   = (const float*)d_in[13];
  const float* rpb   = (const float*)d_in[14];
  const float* ns    = (const float*)d_in[15];

  float* out  = (float*)d_out;
  float* attn = out + (size_t)ROWS*D_DIM;

  char* outb = (char*)d_out;
  bf16_t* x_bf  = (bf16_t*)outb;            // dead after Wv GEMM
  bf16_t* p_bf  = (bf16_t*)outb;            // written by scores, read by PV
  bf16_t* Wv_t  = (bf16_t*)(outb + 33554432ull);
  bf16_t* Wmx_t = (bf16_t*)(outb + 34603008ull);
  bf16_t* Wh_t  = (bf16_t*)(outb + 36831232ull);

  const size_t WS_NEED = 310378496ull;
  if (ws_size < WS_NEED) return;
  char* wsb = (char*)d_ws;
  bf16_t* mx_bf   = (bf16_t*)(wsb);
  bf16_t* vt      = (bf16_t*)(wsb + 33554432ull);
  bf16_t* base_bf = (bf16_t*)(wsb + 100663296ull);
  bf16_t* hr_bf   = (bf16_t*)(wsb + 243269632ull);
  float*  carry   = (float*)(wsb + 100663296ull);
  bf16_t* h2_bf   = mx_bf;

  // weight transposes (one launch)
  transpose_all_kernel<<<2112, 256, 0, stream>>>(Wv, Wmx, Wh, Wv_t, Wmx_t, Wh_t);
  // EMA segmented scan (also produces x_bf)
  ema_carry_kernel<<<1024, 256, 0, stream>>>(x, delta, alpha, x_bf, carry);
  ema_combine_kernel<<<32, 256, 0, stream>>>(delta, alpha, carry);
  ema_apply_kernel<<<1024, 256, 0, stream>>>(x_bf, delta, alpha, beta, gamma,
                                             omega, carry, mx_bf);
  // vt = silu(x @ Wv + bv), transposed per 128-chunk
  mfma_gemm_v_kernel<<<2048, 256, 0, stream>>>(x_bf, Wv_t, bv, vt, 8, D_DIM);
  // base = mx @ Wmx + bmx
  mfma_gemm_kernel<<<4352, 256, 0, stream>>>(
      mx_bf, Wmx_t, bmx, nullptr, 0, base_bf, BASE_N, D_DIM, 17, 0);
  // attn probs (fp32 -> d_out, bf16 -> p_bf)
  attn_scores_mfma_kernel<<<B_DIM*NC, 256, 0, stream>>>(
      base_bf, qkg, qkb, rpb, attn, p_bf);
  // hr = (P @ V) * silu(r)
  attn_pv_kernel<<<2048, 256, 0, stream>>>(p_bf, vt, base_bf, hr_bf);
  // h2 = silu(hx + hr @ Wh + bh)
  mfma_gemm_kernel<<<1024, 256, 0, stream>>>(
      hr_bf, Wh_t, bh, base_bf + 1664, BASE_N, h2_bf, D_DIM, H_DIM, 4, 1);
  // gated residual + RMSNorm
  final_kernel<<<ROWS, 64, 0, stream>>>(x, h2_bf, base_bf, ns, out);
}